// Round 6
// baseline (782.494 us; speedup 1.0000x reference)
//
#include <hip/hip_runtime.h>

#define N_NODES 100000
#define N_EDGES 1600000
#define STRN 264        // node LDS row stride in ushorts (256 + 8 pad)
#define NBLK_SCAN 391   // ceil(100000/256)

typedef __attribute__((ext_vector_type(4))) float floatx4;
typedef __attribute__((ext_vector_type(8))) __bf16 bf16x8;
typedef __attribute__((ext_vector_type(8))) unsigned short ushort8;
typedef __attribute__((ext_vector_type(4))) unsigned short ushort4v;

// ---- ws layout (bytes) ----
#define WS_AGGR   0ull                        // 51,200,000  fp32 [N][128]
#define WS_COUNTS 51200000ull                 // 400,384     int[100096]
#define WS_OFFS   51600384ull                 // 400,384
#define WS_PART   52000768ull                 // 2,048       int[512]
#define WS_DSTS   52002816ull                 // 6,400,000   int[E] (dst-sorted)
#define WS_ATTRS  58402816ull                 // 32,000,000  fp32 [E][5] (dst-sorted)
#define WS_W2     90402816ull                 // Wm2 bf16 [128][128]
#define WS_W3     (WS_W2 + 32768ull)
#define WS_WU1    (WS_W3 + 32768ull)          // Wu1 bf16 padded [224][256]
#define WS_WU2    (WS_WU1 + 114688ull)        // Wu2 bf16 padded [192][224]
#define WS_WU3    (WS_WU2 + 86016ull)         // Wu3 bf16 padded [128][192]

__device__ __forceinline__ unsigned short tobf(float f) {
  return __builtin_bit_cast(unsigned short, (__bf16)f);
}

__device__ __forceinline__ float leaky(float v) { return fmaxf(v, 0.01f * v); }

// XOR-swizzled ushort index into a [128 rows][128 ch] bf16 LDS tile.
__device__ __forceinline__ int swz(int row, int ch) {
  return row * 128 + (ch ^ ((row & 7) << 3));
}

// fp32 msg slab index: [128 edges][16 ch]. Row-swap er = e ^ bit5 spreads the
// 4 walk windows across both 16-bank halves (4-way -> 2-way on walk reads).
// Pure wave-private address bijection: logical e used on write AND read.
__device__ __forceinline__ int msw(int e, int ch) {
  int er = e ^ ((e >> 5) & 1);
  return er * 16 + (ch ^ (((e >> 1) & 3) << 2));
}

// ---------------- weight prep: fp32 -> bf16 (+ zero padding) ----------------
__global__ void prep_kernel(const float* __restrict__ Wm2, const float* __restrict__ Wm3,
                            const float* __restrict__ Wu1, const float* __restrict__ Wu2,
                            const float* __restrict__ Wu3,
                            unsigned short* __restrict__ o2, unsigned short* __restrict__ o3,
                            unsigned short* __restrict__ o1p, unsigned short* __restrict__ o2p,
                            unsigned short* __restrict__ o3p) {
  int i = blockIdx.x * 256 + threadIdx.x;
  if (i < 16384) {
    o2[i] = tobf(Wm2[i]);
  } else if (i < 32768) {
    int j = i - 16384; o3[j] = tobf(Wm3[j]);
  } else if (i < 32768 + 57344) {            // Wu1 pad [214][256] -> [224][256]
    int j = i - 32768; int n = j >> 8, k = j & 255;
    o1p[j] = (n < 214) ? tobf(Wu1[n * 256 + k]) : (unsigned short)0;
  } else if (i < 90112 + 43008) {            // Wu2 pad [172][214] -> [192][224]
    int j = i - 90112; int n = j / 224, k = j - n * 224;
    o2p[j] = (n < 172 && k < 214) ? tobf(Wu2[n * 214 + k]) : (unsigned short)0;
  } else if (i < 133120 + 24576) {           // Wu3 pad [128][172] -> [128][192]
    int j = i - 133120; int n = j / 192, k = j - n * 192;
    o3p[j] = (k < 172) ? tobf(Wu3[n * 172 + k]) : (unsigned short)0;
  }
}

// ---------------- counting sort of edges by dst ----------------
__global__ void hist_kernel(const int* __restrict__ dst, int* __restrict__ counts) {
  int e = blockIdx.x * 256 + threadIdx.x;
  if (e < N_EDGES) atomicAdd(&counts[dst[e]], 1);
}

__global__ void scanA_kernel(const int* __restrict__ counts, int* __restrict__ offs,
                             int* __restrict__ partials) {
  __shared__ int tmp[256];
  const int t = threadIdx.x;
  const int i = blockIdx.x * 256 + t;
  int v = (i < N_NODES) ? counts[i] : 0;
  tmp[t] = v;
  __syncthreads();
  for (int off = 1; off < 256; off <<= 1) {
    int a = (t >= off) ? tmp[t - off] : 0;
    __syncthreads();
    tmp[t] += a;
    __syncthreads();
  }
  if (i < N_NODES) offs[i] = tmp[t] - v;  // exclusive
  if (t == 255) partials[blockIdx.x] = tmp[255];
}

__global__ void scanB_kernel(int* __restrict__ partials) {
  __shared__ int tmp[512];
  const int t = threadIdx.x;
  int v = (t < NBLK_SCAN) ? partials[t] : 0;
  tmp[t] = v;
  __syncthreads();
  for (int off = 1; off < 512; off <<= 1) {
    int a = (t >= off) ? tmp[t - off] : 0;
    __syncthreads();
    tmp[t] += a;
    __syncthreads();
  }
  if (t < NBLK_SCAN) partials[t] = tmp[t] - v;  // exclusive
}

// scatter: reorder the edge PAYLOAD (attr rows + dst) into dst-sorted order.
// scanC is fused here: global position = intra-block exclusive (offs) + block
// prefix (parts[d>>8]) -> identical p values, one kernel launch removed.
// Scattered stores use nontemporal hints (bit-identical data, less L2 churn).
__global__ void scatter_kernel(const int* __restrict__ dst, int* __restrict__ offs,
                               const int* __restrict__ parts,
                               const float* __restrict__ attr,
                               float* __restrict__ attrS, int* __restrict__ dsts) {
  int e = blockIdx.x * 256 + threadIdx.x;
  if (e < N_EDGES) {
    int d = dst[e];
    int p = atomicAdd(&offs[d], 1) + parts[d >> 8];
    __builtin_nontemporal_store(d, &dsts[p]);
    const float* a = attr + (size_t)e * 5;
    float a0 = a[0], a1 = a[1], a2 = a[2], a3 = a[3], a4 = a[4];
    float* o = attrS + (size_t)p * 5;
    __builtin_nontemporal_store(a0, o + 0);
    __builtin_nontemporal_store(a1, o + 1);
    __builtin_nontemporal_store(a2, o + 2);
    __builtin_nontemporal_store(a3, o + 3);
    __builtin_nontemporal_store(a4, o + 4);
  }
}

// ---------------- edge kernel (round-4 verified structure) ----------------
// Swapped-operand MFMA: A = weight rows (wave owns 32 output channels, 8 frags
// prefetched into 32 VGPRs -> no latency chain), B = h tile from swizzled LDS.
// LDS 39.4KB -> 4 blocks/CU. Segment walk per wave over its 32 channels from a
// wave-private fp32 slab.
__global__ __launch_bounds__(256, 4) void edge_kernel(
    const float* __restrict__ attrS, const int* __restrict__ dsts,
    const float* __restrict__ Wm1, const float* __restrict__ bm1,
    const unsigned short* __restrict__ W2bf, const float* __restrict__ bm2,
    const unsigned short* __restrict__ W3bf, const float* __restrict__ bm3,
    float* __restrict__ aggr) {
  __shared__ __align__(16) char smem[39424];
  unsigned short* sH = (unsigned short*)(void*)smem;   // [0,32768): h tile bf16, swizzled
  float* sMsg = (float*)(void*)smem;                   // overlay: 4 wave slabs x 2048 fp32
  float* sAttr8 = (float*)(void*)(smem + 32768);       // 4KB: 128x8 attr rows
  float* sWm1F = (float*)(void*)(smem + 36864);        // 2.5KB: 640 floats

  const int t = threadIdx.x;
  const int wave = t >> 6, lane = t & 63;
  const int col = lane & 15, q = lane >> 4;
  const int eb = wave * 32;      // layer-1: this wave's edge rows
  const int wbase = wave * 32;   // layers 2/3: this wave's output channels
  const long blockEdge = (long)blockIdx.x * 128;

  // ---- stage: Wm1 + this block's dst-sorted attr slab (fully coalesced) ----
  for (int i = t; i < 640; i += 256) {
    sWm1F[i] = Wm1[i];
    float v = attrS[blockEdge * 5 + i];
    int e = i / 5, j = i - e * 5;
    sAttr8[e * 8 + j] = v;
  }
  // window w = lane>>4 covers edges [32w,32w+32); lane holds 2 of its dsts
  const int dE0 = dsts[blockEdge + q * 32 + col];
  const int dE1 = dsts[blockEdge + q * 32 + 16 + col];
  __syncthreads();

  // ---- layer 1 (fp32 vector): lane -> channels {lane, lane+64}, wave-own 32 rows ----
  {
    const int c = lane;
    const float* wa = sWm1F + c * 5;
    const float* wb = sWm1F + (c + 64) * 5;
    float wa0 = wa[0], wa1 = wa[1], wa2 = wa[2], wa3 = wa[3], wa4 = wa[4];
    float wb0 = wb[0], wb1 = wb[1], wb2 = wb[2], wb3 = wb[3], wb4 = wb[4];
    float ba = bm1[c], bb = bm1[c + 64];
#pragma unroll 4
    for (int e = 0; e < 32; e++) {
      const float* ar = sAttr8 + (eb + e) * 8;
      float4 a = *(const float4*)ar;
      float a4 = ar[4];
      float ha = fmaf(a.x, wa0, fmaf(a.y, wa1, fmaf(a.z, wa2, fmaf(a.w, wa3, fmaf(a4, wa4, ba)))));
      float hb = fmaf(a.x, wb0, fmaf(a.y, wb1, fmaf(a.z, wb2, fmaf(a.w, wb3, fmaf(a4, wb4, bb)))));
      sH[swz(eb + e, c)] = tobf(leaky(ha));
      sH[swz(eb + e, c + 64)] = tobf(leaky(hb));
    }
  }
  __syncthreads();  // layer-2 B-reads span all edge rows

  floatx4 acc[2][8];

  // ---- layer 2: A = W2 rows [wbase,wbase+32), prefetched; B = h from LDS ----
  {
    bf16x8 w2f[2][4];
#pragma unroll
    for (int i = 0; i < 2; i++)
#pragma unroll
      for (int ks = 0; ks < 4; ks++)
        w2f[i][ks] = *(const bf16x8*)(const void*)
            &W2bf[(wbase + i * 16 + col) * 128 + ks * 32 + q * 8];
#pragma unroll
    for (int i = 0; i < 2; i++)
#pragma unroll
      for (int j = 0; j < 8; j++) acc[i][j] = (floatx4){0.f, 0.f, 0.f, 0.f};
#pragma unroll
    for (int ks = 0; ks < 4; ks++) {
      const int kk = ks * 32 + q * 8;
#pragma unroll
      for (int et = 0; et < 8; et++) {
        bf16x8 hb = *(const bf16x8*)(const void*)&sH[swz(et * 16 + col, kk)];
        acc[0][et] = __builtin_amdgcn_mfma_f32_16x16x32_bf16(w2f[0][ks], hb, acc[0][et], 0, 0, 0);
        acc[1][et] = __builtin_amdgcn_mfma_f32_16x16x32_bf16(w2f[1][ks], hb, acc[1][et], 0, 0, 0);
      }
    }
  }
  __syncthreads();  // all waves' layer-2 reads done before h2 overwrites sH

  // ---- layer-2 epilogue: D[n][e] -> h2 back to sH (row=e, ch=n) ----
  {
    float4 b2lo = *(const float4*)&bm2[wbase + q * 4];
    float4 b2hi = *(const float4*)&bm2[wbase + 16 + q * 4];
#pragma unroll
    for (int et = 0; et < 8; et++) {
      const int e = et * 16 + col;
#pragma unroll
      for (int r = 0; r < 4; r++) {
        sH[swz(e, wbase + q * 4 + r)] = tobf(leaky(acc[0][et][r] + ((const float*)&b2lo)[r]));
        sH[swz(e, wbase + 16 + q * 4 + r)] = tobf(leaky(acc[1][et][r] + ((const float*)&b2hi)[r]));
      }
    }
  }
  __syncthreads();  // h2 complete before layer-3 reads

  // ---- layer 3: A = W3 rows, prefetched; B = h2 from LDS ----
  {
    bf16x8 w3f[2][4];
#pragma unroll
    for (int i = 0; i < 2; i++)
#pragma unroll
      for (int ks = 0; ks < 4; ks++)
        w3f[i][ks] = *(const bf16x8*)(const void*)
            &W3bf[(wbase + i * 16 + col) * 128 + ks * 32 + q * 8];
#pragma unroll
    for (int i = 0; i < 2; i++)
#pragma unroll
      for (int j = 0; j < 8; j++) acc[i][j] = (floatx4){0.f, 0.f, 0.f, 0.f};
#pragma unroll
    for (int ks = 0; ks < 4; ks++) {
      const int kk = ks * 32 + q * 8;
#pragma unroll
      for (int et = 0; et < 8; et++) {
        bf16x8 hb = *(const bf16x8*)(const void*)&sH[swz(et * 16 + col, kk)];
        acc[0][et] = __builtin_amdgcn_mfma_f32_16x16x32_bf16(w3f[0][ks], hb, acc[0][et], 0, 0, 0);
        acc[1][et] = __builtin_amdgcn_mfma_f32_16x16x32_bf16(w3f[1][ks], hb, acc[1][et], 0, 0, 0);
      }
    }
  }
  __syncthreads();  // all sH reads done; smem becomes per-wave sMsg slabs

  // ---- two 16-channel chunks: msg fp32 -> wave-private slab, then segment walk ----
  const int wslab = wave * 2048;
#pragma unroll
  for (int c = 0; c < 2; c++) {
    float4 b3 = *(const float4*)&bm3[wbase + c * 16 + q * 4];
#pragma unroll
    for (int et = 0; et < 8; et++) {
      const int e = et * 16 + col;
#pragma unroll
      for (int r = 0; r < 4; r++)
        sMsg[wslab + msw(e, q * 4 + r)] = acc[c][et][r] + ((const float*)&b3)[r];
    }
    asm volatile("s_waitcnt lgkmcnt(0)" ::: "memory");  // wave-local slab visible

    // lane -> (ch = lane&15, window = q of 32 edges)
    const int ch = col;
    const int chG = wbase + c * 16 + ch;
    float accv = 0.f;
    int dprev = __shfl(dE0, lane & 48);
#pragma unroll 8
    for (int it = 0; it < 32; it++) {
      int d = __shfl((it < 16) ? dE0 : dE1, (lane & 48) + (it & 15));
      float v = sMsg[wslab + msw(q * 32 + it, ch)];
      if (d != dprev) {
        atomicAdd(&aggr[(size_t)dprev * 128 + chG], accv);
        accv = 0.f;
        dprev = d;
      }
      accv += v;
    }
    atomicAdd(&aggr[(size_t)dprev * 128 + chG], accv);
  }
}

// ---------------- node layer (swapped-operand MFMA) ----------------
// Wave owns chan tiles {wave + 4j}; A = W rows prefetched per-ks (reused over
// 4 node tiles), B = nodes from LDS. a[c] always loaded in-bounds (no undef
// operand ever reaches an intrinsic); MFMA + epilogue guarded by tile<TILES.
template <int TILES, int CT, int KST, bool FINAL>
__device__ __forceinline__ void layer_node_sw(unsigned short* __restrict__ sX,
                                              const unsigned short* __restrict__ W,
                                              const float* __restrict__ bias, int biasLim,
                                              int wave, int lane, int nodeGBase,
                                              float* __restrict__ out) {
  const int col = lane & 15, q = lane >> 4;
  const int K = KST * 32;
  floatx4 acc[CT][4];
#pragma unroll
  for (int c = 0; c < CT; c++)
#pragma unroll
    for (int n = 0; n < 4; n++) acc[c][n] = (floatx4){0.f, 0.f, 0.f, 0.f};

#pragma unroll
  for (int ks = 0; ks < KST; ks++) {
    const int kk = ks * 32 + q * 8;
    bf16x8 a[CT];
#pragma unroll
    for (int c = 0; c < CT; c++) {
      const int tile = wave + 4 * c;
      const int tc = (tile < TILES) ? tile : 0;  // always defined, always in-bounds
      a[c] = *(const bf16x8*)(const void*)&W[(tc * 16 + col) * K + kk];
    }
    bf16x8 b[4];
#pragma unroll
    for (int n = 0; n < 4; n++)
      b[n] = *(const bf16x8*)(const void*)&sX[(n * 16 + col) * STRN + kk];
#pragma unroll
    for (int c = 0; c < CT; c++) {
      if (wave + 4 * c < TILES) {
#pragma unroll
        for (int n = 0; n < 4; n++)
          acc[c][n] = __builtin_amdgcn_mfma_f32_16x16x32_bf16(a[c], b[n], acc[c][n], 0, 0, 0);
      }
    }
  }
  __syncthreads();  // all waves done reading sX before epilogue overwrites

#pragma unroll
  for (int c = 0; c < CT; c++) {
    const int tile = wave + 4 * c;
    if (tile < TILES) {
      float bv[4];
#pragma unroll
      for (int r = 0; r < 4; r++) {
        const int ch = tile * 16 + q * 4 + r;
        bv[r] = (ch < biasLim) ? bias[ch] : 0.f;
      }
#pragma unroll
      for (int n = 0; n < 4; n++) {
        const int node = n * 16 + col;
        if (!FINAL) {
          ushort4v p;
#pragma unroll
          for (int r = 0; r < 4; r++) p[r] = tobf(leaky(acc[c][n][r] + bv[r]));
          *(ushort4v*)(void*)&sX[node * STRN + tile * 16 + q * 4] = p;
        } else {
          const long ng = (long)nodeGBase + node;
          if (ng < N_NODES) {
            float4 p = make_float4(acc[c][n][0] + bv[0], acc[c][n][1] + bv[1],
                                   acc[c][n][2] + bv[2], acc[c][n][3] + bv[3]);
            *(float4*)(void*)&out[ng * 128 + tile * 16 + q * 4] = p;
          }
        }
      }
    }
  }
  if (!FINAL) __syncthreads();  // writes visible before next layer reads
}

// ---------------- node kernel: LN(concat) + MLP ----------------
__global__ __launch_bounds__(256, 4) void node_kernel(
    const float* __restrict__ x, const float* __restrict__ aggr,
    const float* __restrict__ lng, const float* __restrict__ lnb,
    const unsigned short* __restrict__ Wu1p, const float* __restrict__ bu1,
    const unsigned short* __restrict__ Wu2p, const float* __restrict__ bu2,
    const unsigned short* __restrict__ Wu3p, const float* __restrict__ bu3,
    float* __restrict__ out) {
  __shared__ unsigned short sX[64 * STRN];  // [node][c] bf16, padded stride
  __shared__ float sG[256], sB[256];
  const int t = threadIdx.x;
  const int wave = t >> 6, lane = t & 63;
  sG[t] = lng[t];
  sB[t] = lnb[t];

  // LayerNorm over cat=[x,aggr] (fp32). 4 threads per node.
  const int nl = t >> 2;
  const int part = t & 3;
  const long nodeG = (long)blockIdx.x * 64 + nl;
  const bool valid = nodeG < N_NODES;
  const float* src = (part < 2) ? (x + nodeG * 128 + part * 64)
                                : (aggr + nodeG * 128 + (part - 2) * 64);
  float s = 0.f, ss = 0.f;
  if (valid) {
#pragma unroll
    for (int i = 0; i < 16; i++) {
      float4 a = *(const float4*)(src + i * 4);
      s += a.x + a.y + a.z + a.w;
      ss += a.x * a.x + a.y * a.y + a.z * a.z + a.w * a.w;
    }
  }
  s += __shfl_xor(s, 1); s += __shfl_xor(s, 2);
  ss += __shfl_xor(ss, 1); ss += __shfl_xor(ss, 2);
  const float mean = s * (1.f / 256.f);
  const float var = ss * (1.f / 256.f) - mean * mean;
  const float rstd = rsqrtf(var + 1e-5f);
  __syncthreads();  // sG/sB visible
  const int cb = part * 64;
#pragma unroll
  for (int i = 0; i < 16; i++) {
    float4 a = valid ? *(const float4*)(src + i * 4) : make_float4(0.f, 0.f, 0.f, 0.f);
    int c = cb + i * 4;
    ushort4v p;
    p[0] = tobf((a.x - mean) * rstd * sG[c + 0] + sB[c + 0]);
    p[1] = tobf((a.y - mean) * rstd * sG[c + 1] + sB[c + 1]);
    p[2] = tobf((a.z - mean) * rstd * sG[c + 2] + sB[c + 2]);
    p[3] = tobf((a.w - mean) * rstd * sG[c + 3] + sB[c + 3]);
    *(ushort4v*)(void*)&sX[nl * STRN + c] = p;
  }
  __syncthreads();

  const int nodeGBase = blockIdx.x * 64;
  layer_node_sw<14, 4, 8, false>(sX, Wu1p, bu1, 214, wave, lane, nodeGBase, nullptr);
  layer_node_sw<12, 3, 7, false>(sX, Wu2p, bu2, 172, wave, lane, nodeGBase, nullptr);
  layer_node_sw<8, 2, 6, true>(sX, Wu3p, bu3, 128, wave, lane, nodeGBase, out);
}

// ---------------- launch ----------------
extern "C" void kernel_launch(void* const* d_in, const int* in_sizes, int n_in,
                              void* d_out, int out_size, void* d_ws, size_t ws_size,
                              hipStream_t stream) {
  const float* x    = (const float*)d_in[0];
  const int*   eidx = (const int*)d_in[1];
  const float* attr = (const float*)d_in[2];
  const float* Wm1  = (const float*)d_in[3];
  const float* bm1  = (const float*)d_in[4];
  const float* Wm2  = (const float*)d_in[5];
  const float* bm2  = (const float*)d_in[6];
  const float* Wm3  = (const float*)d_in[7];
  const float* bm3  = (const float*)d_in[8];
  const float* lng  = (const float*)d_in[9];
  const float* lnb  = (const float*)d_in[10];
  const float* Wu1  = (const float*)d_in[11];
  const float* bu1  = (const float*)d_in[12];
  const float* Wu2  = (const float*)d_in[13];
  const float* bu2  = (const float*)d_in[14];
  const float* Wu3  = (const float*)d_in[15];
  const float* bu3  = (const float*)d_in[16];
  float* out = (float*)d_out;

  char* ws = (char*)d_ws;
  float* aggr  = (float*)(ws + WS_AGGR);
  int* counts  = (int*)(ws + WS_COUNTS);
  int* offs    = (int*)(ws + WS_OFFS);
  int* parts   = (int*)(ws + WS_PART);
  int* dsts    = (int*)(ws + WS_DSTS);
  float* attrS = (float*)(ws + WS_ATTRS);
  unsigned short* W2bf = (unsigned short*)(ws + WS_W2);
  unsigned short* W3bf = (unsigned short*)(ws + WS_W3);
  unsigned short* Wu1p = (unsigned short*)(ws + WS_WU1);
  unsigned short* Wu2p = (unsigned short*)(ws + WS_WU2);
  unsigned short* Wu3p = (unsigned short*)(ws + WS_WU3);

  const int* dst = eidx + N_EDGES;  // edge_index[1]

  // counting sort of edges by dst (payload reorder: attrS + dsts); scanC fused
  // into scatter via parts[d>>8].
  hipMemsetAsync(counts, 0, 400384, stream);
  hist_kernel<<<6250, 256, 0, stream>>>(dst, counts);
  scanA_kernel<<<NBLK_SCAN, 256, 0, stream>>>(counts, offs, parts);
  scanB_kernel<<<1, 512, 0, stream>>>(parts);
  scatter_kernel<<<6250, 256, 0, stream>>>(dst, offs, parts, attr, attrS, dsts);

  hipMemsetAsync(aggr, 0, (size_t)N_NODES * 128 * sizeof(float), stream);
  prep_kernel<<<616, 256, 0, stream>>>(Wm2, Wm3, Wu1, Wu2, Wu3, W2bf, W3bf, Wu1p, Wu2p, Wu3p);

  edge_kernel<<<N_EDGES / 128, 256, 0, stream>>>(attrS, dsts, Wm1, bm1, W2bf, bm2, W3bf,
                                                 bm3, aggr);
  node_kernel<<<(N_NODES + 63) / 64, 256, 0, stream>>>(x, aggr, lng, lnb, Wu1p, bu1, Wu2p, bu2,
                                                       Wu3p, bu3, out);
}

// Round 8
// 731.180 us; speedup vs baseline: 1.0702x; 1.0702x over previous
//
#include <hip/hip_runtime.h>

#define N_NODES 100000
#define N_EDGES 1600000
#define STRN 264        // node LDS row stride in ushorts (256 + 8 pad)
#define NBLK_SCAN 391   // ceil(100000/256)

// msg fixed-point scale: aggr accumulates round(v * 2^12) in int32.
// Integer adds are associative -> aggr is EXACTLY order-independent.
#define MSG_SCALE 4096.0f
#define MSG_INV   0.000244140625f

typedef __attribute__((ext_vector_type(4))) float floatx4;
typedef __attribute__((ext_vector_type(8))) __bf16 bf16x8;
typedef __attribute__((ext_vector_type(8))) unsigned short ushort8;
typedef __attribute__((ext_vector_type(4))) unsigned short ushort4v;

// ---- ws layout (bytes) ----
#define WS_AGGR   0ull                        // 51,200,000  int32 [N][128] (fixed-point)
#define WS_COUNTS 51200000ull                 // 400,384     int[100096]
#define WS_OFFS   51600384ull                 // 400,384
#define WS_PART   52000768ull                 // 2,048       int[512]
#define WS_DSTS   52002816ull                 // 6,400,000   int[E] (dst-sorted)
#define WS_ATTRS  58402816ull                 // 32,000,000  fp32 [E][5] (dst-sorted)
#define WS_W2     90402816ull                 // Wm2 bf16 [128][128]
#define WS_W3     (WS_W2 + 32768ull)
#define WS_WU1    (WS_W3 + 32768ull)          // Wu1 bf16 padded [224][256]
#define WS_WU2    (WS_WU1 + 114688ull)        // Wu2 bf16 padded [192][224]
#define WS_WU3    (WS_WU2 + 86016ull)         // Wu3 bf16 padded [128][192]

__device__ __forceinline__ unsigned short tobf(float f) {
  return __builtin_bit_cast(unsigned short, (__bf16)f);
}

__device__ __forceinline__ float leaky(float v) { return fmaxf(v, 0.01f * v); }

// XOR-swizzled ushort index into a [128 rows][128 ch] bf16 LDS tile.
__device__ __forceinline__ int swz(int row, int ch) {
  return row * 128 + (ch ^ ((row & 7) << 3));
}

// fp32 msg slab index: [128 edges][16 ch].
__device__ __forceinline__ int msw(int e, int ch) {
  return e * 16 + (ch ^ (((e >> 1) & 3) << 2));
}

// ---------------- weight prep: fp32 -> bf16 (+ zero padding) ----------------
__global__ void prep_kernel(const float* __restrict__ Wm2, const float* __restrict__ Wm3,
                            const float* __restrict__ Wu1, const float* __restrict__ Wu2,
                            const float* __restrict__ Wu3,
                            unsigned short* __restrict__ o2, unsigned short* __restrict__ o3,
                            unsigned short* __restrict__ o1p, unsigned short* __restrict__ o2p,
                            unsigned short* __restrict__ o3p) {
  int i = blockIdx.x * 256 + threadIdx.x;
  if (i < 16384) {
    o2[i] = tobf(Wm2[i]);
  } else if (i < 32768) {
    int j = i - 16384; o3[j] = tobf(Wm3[j]);
  } else if (i < 32768 + 57344) {            // Wu1 pad [214][256] -> [224][256]
    int j = i - 32768; int n = j >> 8, k = j & 255;
    o1p[j] = (n < 214) ? tobf(Wu1[n * 256 + k]) : (unsigned short)0;
  } else if (i < 90112 + 43008) {            // Wu2 pad [172][214] -> [192][224]
    int j = i - 90112; int n = j / 224, k = j - n * 224;
    o2p[j] = (n < 172 && k < 214) ? tobf(Wu2[n * 214 + k]) : (unsigned short)0;
  } else if (i < 133120 + 24576) {           // Wu3 pad [128][172] -> [128][192]
    int j = i - 133120; int n = j / 192, k = j - n * 192;
    o3p[j] = (k < 172) ? tobf(Wu3[n * 172 + k]) : (unsigned short)0;
  }
}

// ---------------- counting sort of edges by dst ----------------
__global__ void hist_kernel(const int* __restrict__ dst, int* __restrict__ counts) {
  int e = blockIdx.x * 256 + threadIdx.x;
  if (e < N_EDGES) atomicAdd(&counts[dst[e]], 1);
}

__global__ void scanA_kernel(const int* __restrict__ counts, int* __restrict__ offs,
                             int* __restrict__ partials) {
  __shared__ int tmp[256];
  const int t = threadIdx.x;
  const int i = blockIdx.x * 256 + t;
  int v = (i < N_NODES) ? counts[i] : 0;
  tmp[t] = v;
  __syncthreads();
  for (int off = 1; off < 256; off <<= 1) {
    int a = (t >= off) ? tmp[t - off] : 0;
    __syncthreads();
    tmp[t] += a;
    __syncthreads();
  }
  if (i < N_NODES) offs[i] = tmp[t] - v;  // exclusive
  if (t == 255) partials[blockIdx.x] = tmp[255];
}

__global__ void scanB_kernel(int* __restrict__ partials) {
  __shared__ int tmp[512];
  const int t = threadIdx.x;
  int v = (t < NBLK_SCAN) ? partials[t] : 0;
  tmp[t] = v;
  __syncthreads();
  for (int off = 1; off < 512; off <<= 1) {
    int a = (t >= off) ? tmp[t - off] : 0;
    __syncthreads();
    tmp[t] += a;
    __syncthreads();
  }
  if (t < NBLK_SCAN) partials[t] = tmp[t] - v;  // exclusive
}

__global__ void scanC_kernel(int* __restrict__ offs, const int* __restrict__ partials) {
  int i = blockIdx.x * 256 + threadIdx.x;
  if (i < N_NODES) offs[i] += partials[blockIdx.x];
}

// scatter: reorder the edge PAYLOAD (attr rows + dst) into dst-sorted order.
// The within-dst permutation (atomicAdd arrival order) is nondeterministic, but
// the int32 fixed-point aggregation downstream is exactly order-independent, so
// the final output no longer depends on this permutation.
__global__ void scatter_kernel(const int* __restrict__ dst, int* __restrict__ offs,
                               const float* __restrict__ attr,
                               float* __restrict__ attrS, int* __restrict__ dsts) {
  int e = blockIdx.x * 256 + threadIdx.x;
  if (e < N_EDGES) {
    int d = dst[e];
    int p = atomicAdd(&offs[d], 1);
    dsts[p] = d;
    const float* a = attr + (size_t)e * 5;
    float a0 = a[0], a1 = a[1], a2 = a[2], a3 = a[3], a4 = a[4];
    float* o = attrS + (size_t)p * 5;
    o[0] = a0; o[1] = a1; o[2] = a2; o[3] = a3; o[4] = a4;
  }
}

// ---------------- edge kernel (r4 structure; int32 fixed-point aggregation) ----------------
// Swapped-operand MFMA: A = weight rows (wave owns 32 output channels, 8 frags
// prefetched into 32 VGPRs -> no latency chain), B = h tile from swizzled LDS.
// LDS 39.4KB -> 4 blocks/CU. Segment walk per wave over its 32 channels from a
// wave-private fp32 slab; each msg rounded ONCE to 2^-12 grid, accumulated in
// int32 -> aggr total is exactly Sum(round(v*S)) independent of edge order.
__global__ __launch_bounds__(256, 4) void edge_kernel(
    const float* __restrict__ attrS, const int* __restrict__ dsts,
    const float* __restrict__ Wm1, const float* __restrict__ bm1,
    const unsigned short* __restrict__ W2bf, const float* __restrict__ bm2,
    const unsigned short* __restrict__ W3bf, const float* __restrict__ bm3,
    int* __restrict__ aggr) {
  __shared__ __align__(16) char smem[39424];
  unsigned short* sH = (unsigned short*)(void*)smem;   // [0,32768): h tile bf16, swizzled
  float* sMsg = (float*)(void*)smem;                   // overlay: 4 wave slabs x 2048 fp32
  float* sAttr8 = (float*)(void*)(smem + 32768);       // 4KB: 128x8 attr rows
  float* sWm1F = (float*)(void*)(smem + 36864);        // 2.5KB: 640 floats

  const int t = threadIdx.x;
  const int wave = t >> 6, lane = t & 63;
  const int col = lane & 15, q = lane >> 4;
  const int eb = wave * 32;      // layer-1: this wave's edge rows
  const int wbase = wave * 32;   // layers 2/3: this wave's output channels
  const long blockEdge = (long)blockIdx.x * 128;

  // ---- stage: Wm1 + this block's dst-sorted attr slab (fully coalesced) ----
  for (int i = t; i < 640; i += 256) {
    sWm1F[i] = Wm1[i];
    float v = attrS[blockEdge * 5 + i];
    int e = i / 5, j = i - e * 5;
    sAttr8[e * 8 + j] = v;
  }
  // window w = lane>>4 covers edges [32w,32w+32); lane holds 2 of its dsts
  const int dE0 = dsts[blockEdge + q * 32 + col];
  const int dE1 = dsts[blockEdge + q * 32 + 16 + col];
  __syncthreads();

  // ---- layer 1 (fp32 vector): lane -> channels {lane, lane+64}, wave-own 32 rows ----
  {
    const int c = lane;
    const float* wa = sWm1F + c * 5;
    const float* wb = sWm1F + (c + 64) * 5;
    float wa0 = wa[0], wa1 = wa[1], wa2 = wa[2], wa3 = wa[3], wa4 = wa[4];
    float wb0 = wb[0], wb1 = wb[1], wb2 = wb[2], wb3 = wb[3], wb4 = wb[4];
    float ba = bm1[c], bb = bm1[c + 64];
#pragma unroll 4
    for (int e = 0; e < 32; e++) {
      const float* ar = sAttr8 + (eb + e) * 8;
      float4 a = *(const float4*)ar;
      float a4 = ar[4];
      float ha = fmaf(a.x, wa0, fmaf(a.y, wa1, fmaf(a.z, wa2, fmaf(a.w, wa3, fmaf(a4, wa4, ba)))));
      float hb = fmaf(a.x, wb0, fmaf(a.y, wb1, fmaf(a.z, wb2, fmaf(a.w, wb3, fmaf(a4, wb4, bb)))));
      sH[swz(eb + e, c)] = tobf(leaky(ha));
      sH[swz(eb + e, c + 64)] = tobf(leaky(hb));
    }
  }
  __syncthreads();  // layer-2 B-reads span all edge rows

  floatx4 acc[2][8];

  // ---- layer 2: A = W2 rows [wbase,wbase+32), prefetched; B = h from LDS ----
  {
    bf16x8 w2f[2][4];
#pragma unroll
    for (int i = 0; i < 2; i++)
#pragma unroll
      for (int ks = 0; ks < 4; ks++)
        w2f[i][ks] = *(const bf16x8*)(const void*)
            &W2bf[(wbase + i * 16 + col) * 128 + ks * 32 + q * 8];
#pragma unroll
    for (int i = 0; i < 2; i++)
#pragma unroll
      for (int j = 0; j < 8; j++) acc[i][j] = (floatx4){0.f, 0.f, 0.f, 0.f};
#pragma unroll
    for (int ks = 0; ks < 4; ks++) {
      const int kk = ks * 32 + q * 8;
#pragma unroll
      for (int et = 0; et < 8; et++) {
        bf16x8 hb = *(const bf16x8*)(const void*)&sH[swz(et * 16 + col, kk)];
        acc[0][et] = __builtin_amdgcn_mfma_f32_16x16x32_bf16(w2f[0][ks], hb, acc[0][et], 0, 0, 0);
        acc[1][et] = __builtin_amdgcn_mfma_f32_16x16x32_bf16(w2f[1][ks], hb, acc[1][et], 0, 0, 0);
      }
    }
  }
  __syncthreads();  // all waves' layer-2 reads done before h2 overwrites sH

  // ---- layer-2 epilogue: D[n][e] -> h2 back to sH (row=e, ch=n) ----
  {
    float4 b2lo = *(const float4*)&bm2[wbase + q * 4];
    float4 b2hi = *(const float4*)&bm2[wbase + 16 + q * 4];
#pragma unroll
    for (int et = 0; et < 8; et++) {
      const int e = et * 16 + col;
#pragma unroll
      for (int r = 0; r < 4; r++) {
        sH[swz(e, wbase + q * 4 + r)] = tobf(leaky(acc[0][et][r] + ((const float*)&b2lo)[r]));
        sH[swz(e, wbase + 16 + q * 4 + r)] = tobf(leaky(acc[1][et][r] + ((const float*)&b2hi)[r]));
      }
    }
  }
  __syncthreads();  // h2 complete before layer-3 reads

  // ---- layer 3: A = W3 rows, prefetched; B = h2 from LDS ----
  {
    bf16x8 w3f[2][4];
#pragma unroll
    for (int i = 0; i < 2; i++)
#pragma unroll
      for (int ks = 0; ks < 4; ks++)
        w3f[i][ks] = *(const bf16x8*)(const void*)
            &W3bf[(wbase + i * 16 + col) * 128 + ks * 32 + q * 8];
#pragma unroll
    for (int i = 0; i < 2; i++)
#pragma unroll
      for (int j = 0; j < 8; j++) acc[i][j] = (floatx4){0.f, 0.f, 0.f, 0.f};
#pragma unroll
    for (int ks = 0; ks < 4; ks++) {
      const int kk = ks * 32 + q * 8;
#pragma unroll
      for (int et = 0; et < 8; et++) {
        bf16x8 hb = *(const bf16x8*)(const void*)&sH[swz(et * 16 + col, kk)];
        acc[0][et] = __builtin_amdgcn_mfma_f32_16x16x32_bf16(w3f[0][ks], hb, acc[0][et], 0, 0, 0);
        acc[1][et] = __builtin_amdgcn_mfma_f32_16x16x32_bf16(w3f[1][ks], hb, acc[1][et], 0, 0, 0);
      }
    }
  }
  __syncthreads();  // all sH reads done; smem becomes per-wave sMsg slabs

  // ---- two 16-channel chunks: msg fp32 -> wave-private slab, then segment walk ----
  const int wslab = wave * 2048;
#pragma unroll
  for (int c = 0; c < 2; c++) {
    float4 b3 = *(const float4*)&bm3[wbase + c * 16 + q * 4];
#pragma unroll
    for (int et = 0; et < 8; et++) {
      const int e = et * 16 + col;
#pragma unroll
      for (int r = 0; r < 4; r++)
        sMsg[wslab + msw(e, q * 4 + r)] = acc[c][et][r] + ((const float*)&b3)[r];
    }
    asm volatile("s_waitcnt lgkmcnt(0)" ::: "memory");  // wave-local slab visible

    // lane -> (ch = lane&15, window = q of 32 edges)
    const int ch = col;
    const int chG = wbase + c * 16 + ch;
    int accv = 0;
    int dprev = __shfl(dE0, lane & 48);
#pragma unroll 8
    for (int it = 0; it < 32; it++) {
      int d = __shfl((it < 16) ? dE0 : dE1, (lane & 48) + (it & 15));
      float v = sMsg[wslab + msw(q * 32 + it, ch)];
      int iv = __float2int_rn(v * MSG_SCALE);  // one rounding per msg, order-free
      if (d != dprev) {
        atomicAdd(&aggr[(size_t)dprev * 128 + chG], accv);
        accv = 0;
        dprev = d;
      }
      accv += iv;
    }
    atomicAdd(&aggr[(size_t)dprev * 128 + chG], accv);
  }
}

// ---------------- node layer (swapped-operand MFMA, 32-node blocks) ----------------
template <int TILES, int CT, int KST, bool FINAL>
__device__ __forceinline__ void layer_node_sw(unsigned short* __restrict__ sX,
                                              const unsigned short* __restrict__ W,
                                              const float* __restrict__ bias, int biasLim,
                                              int wave, int lane, int nodeGBase,
                                              float* __restrict__ out) {
  const int col = lane & 15, q = lane >> 4;
  const int K = KST * 32;
  floatx4 acc[CT][2];
#pragma unroll
  for (int c = 0; c < CT; c++)
#pragma unroll
    for (int n = 0; n < 2; n++) acc[c][n] = (floatx4){0.f, 0.f, 0.f, 0.f};

#pragma unroll
  for (int ks = 0; ks < KST; ks++) {
    const int kk = ks * 32 + q * 8;
    bf16x8 a[CT];
#pragma unroll
    for (int c = 0; c < CT; c++) {
      const int tile = wave + 4 * c;
      const int tc = (tile < TILES) ? tile : 0;  // always defined, always in-bounds
      a[c] = *(const bf16x8*)(const void*)&W[(tc * 16 + col) * K + kk];
    }
    bf16x8 b[2];
#pragma unroll
    for (int n = 0; n < 2; n++)
      b[n] = *(const bf16x8*)(const void*)&sX[(n * 16 + col) * STRN + kk];
#pragma unroll
    for (int c = 0; c < CT; c++) {
      if (wave + 4 * c < TILES) {
#pragma unroll
        for (int n = 0; n < 2; n++)
          acc[c][n] = __builtin_amdgcn_mfma_f32_16x16x32_bf16(a[c], b[n], acc[c][n], 0, 0, 0);
      }
    }
  }
  __syncthreads();  // all waves done reading sX before epilogue overwrites

#pragma unroll
  for (int c = 0; c < CT; c++) {
    const int tile = wave + 4 * c;
    if (tile < TILES) {
      float bv[4];
#pragma unroll
      for (int r = 0; r < 4; r++) {
        const int ch = tile * 16 + q * 4 + r;
        bv[r] = (ch < biasLim) ? bias[ch] : 0.f;
      }
#pragma unroll
      for (int n = 0; n < 2; n++) {
        const int node = n * 16 + col;
        if (!FINAL) {
          ushort4v p;
#pragma unroll
          for (int r = 0; r < 4; r++) p[r] = tobf(leaky(acc[c][n][r] + bv[r]));
          *(ushort4v*)(void*)&sX[node * STRN + tile * 16 + q * 4] = p;
        } else {
          const long ng = (long)nodeGBase + node;
          if (ng < N_NODES) {
            float4 p = make_float4(acc[c][n][0] + bv[0], acc[c][n][1] + bv[1],
                                   acc[c][n][2] + bv[2], acc[c][n][3] + bv[3]);
            *(float4*)(void*)&out[ng * 128 + tile * 16 + q * 4] = p;
          }
        }
      }
    }
  }
  if (!FINAL) __syncthreads();  // writes visible before next layer reads
}

// ---------------- node kernel: LN(concat) + MLP, 32 nodes/block ----------------
// aggr arrives as int32 fixed-point; conversion iv*MSG_INV is deterministic.
__global__ __launch_bounds__(256, 4) void node_kernel(
    const float* __restrict__ x, const int* __restrict__ aggr,
    const float* __restrict__ lng, const float* __restrict__ lnb,
    const unsigned short* __restrict__ Wu1p, const float* __restrict__ bu1,
    const unsigned short* __restrict__ Wu2p, const float* __restrict__ bu2,
    const unsigned short* __restrict__ Wu3p, const float* __restrict__ bu3,
    float* __restrict__ out) {
  __shared__ unsigned short sX[32 * STRN];  // [node][c] bf16, padded stride
  __shared__ float sG[256], sB[256];
  const int t = threadIdx.x;
  const int wave = t >> 6, lane = t & 63;
  sG[t] = lng[t];
  sB[t] = lnb[t];

  // LayerNorm over cat=[x,aggr] (fp32). 4 threads per node; t<128 active.
  const int nl = t >> 2;
  const int part = t & 3;
  const long nodeG = (long)blockIdx.x * 32 + nl;
  const bool valid = (t < 128) && (nodeG < N_NODES);
  const float* srcF = x + nodeG * 128 + part * 64;
  const int* srcI = aggr + nodeG * 128 + (part - 2) * 64;
  float s = 0.f, ss = 0.f;
  if (valid) {
#pragma unroll
    for (int i = 0; i < 16; i++) {
      float4 a;
      if (part < 2) {
        a = *(const float4*)(srcF + i * 4);
      } else {
        int4 iv = *(const int4*)(srcI + i * 4);
        a = make_float4(iv.x * MSG_INV, iv.y * MSG_INV, iv.z * MSG_INV, iv.w * MSG_INV);
      }
      s += a.x + a.y + a.z + a.w;
      ss += a.x * a.x + a.y * a.y + a.z * a.z + a.w * a.w;
    }
  }
  s += __shfl_xor(s, 1); s += __shfl_xor(s, 2);
  ss += __shfl_xor(ss, 1); ss += __shfl_xor(ss, 2);
  const float mean = s * (1.f / 256.f);
  const float var = ss * (1.f / 256.f) - mean * mean;
  const float rstd = rsqrtf(var + 1e-5f);
  __syncthreads();  // sG/sB visible
  if (valid) {
    const int cb = part * 64;
#pragma unroll
    for (int i = 0; i < 16; i++) {
      float4 a;
      if (part < 2) {
        a = *(const float4*)(srcF + i * 4);
      } else {
        int4 iv = *(const int4*)(srcI + i * 4);
        a = make_float4(iv.x * MSG_INV, iv.y * MSG_INV, iv.z * MSG_INV, iv.w * MSG_INV);
      }
      int c = cb + i * 4;
      ushort4v p;
      p[0] = tobf((a.x - mean) * rstd * sG[c + 0] + sB[c + 0]);
      p[1] = tobf((a.y - mean) * rstd * sG[c + 1] + sB[c + 1]);
      p[2] = tobf((a.z - mean) * rstd * sG[c + 2] + sB[c + 2]);
      p[3] = tobf((a.w - mean) * rstd * sG[c + 3] + sB[c + 3]);
      *(ushort4v*)(void*)&sX[nl * STRN + c] = p;
    }
  }
  __syncthreads();

  const int nodeGBase = blockIdx.x * 32;
  layer_node_sw<14, 4, 8, false>(sX, Wu1p, bu1, 214, wave, lane, nodeGBase, nullptr);
  layer_node_sw<12, 3, 7, false>(sX, Wu2p, bu2, 172, wave, lane, nodeGBase, nullptr);
  layer_node_sw<8, 2, 6, true>(sX, Wu3p, bu3, 128, wave, lane, nodeGBase, out);
}

// ---------------- launch ----------------
extern "C" void kernel_launch(void* const* d_in, const int* in_sizes, int n_in,
                              void* d_out, int out_size, void* d_ws, size_t ws_size,
                              hipStream_t stream) {
  const float* x    = (const float*)d_in[0];
  const int*   eidx = (const int*)d_in[1];
  const float* attr = (const float*)d_in[2];
  const float* Wm1  = (const float*)d_in[3];
  const float* bm1  = (const float*)d_in[4];
  const float* Wm2  = (const float*)d_in[5];
  const float* bm2  = (const float*)d_in[6];
  const float* Wm3  = (const float*)d_in[7];
  const float* bm3  = (const float*)d_in[8];
  const float* lng  = (const float*)d_in[9];
  const float* lnb  = (const float*)d_in[10];
  const float* Wu1  = (const float*)d_in[11];
  const float* bu1  = (const float*)d_in[12];
  const float* Wu2  = (const float*)d_in[13];
  const float* bu2  = (const float*)d_in[14];
  const float* Wu3  = (const float*)d_in[15];
  const float* bu3  = (const float*)d_in[16];
  float* out = (float*)d_out;

  char* ws = (char*)d_ws;
  int* aggr    = (int*)(ws + WS_AGGR);
  int* counts  = (int*)(ws + WS_COUNTS);
  int* offs    = (int*)(ws + WS_OFFS);
  int* parts   = (int*)(ws + WS_PART);
  int* dsts    = (int*)(ws + WS_DSTS);
  float* attrS = (float*)(ws + WS_ATTRS);
  unsigned short* W2bf = (unsigned short*)(ws + WS_W2);
  unsigned short* W3bf = (unsigned short*)(ws + WS_W3);
  unsigned short* Wu1p = (unsigned short*)(ws + WS_WU1);
  unsigned short* Wu2p = (unsigned short*)(ws + WS_WU2);
  unsigned short* Wu3p = (unsigned short*)(ws + WS_WU3);

  const int* dst = eidx + N_EDGES;  // edge_index[1]

  // counting sort of edges by dst (payload reorder: attrS + dsts)
  hipMemsetAsync(counts, 0, 400384, stream);
  hist_kernel<<<6250, 256, 0, stream>>>(dst, counts);
  scanA_kernel<<<NBLK_SCAN, 256, 0, stream>>>(counts, offs, parts);
  scanB_kernel<<<1, 512, 0, stream>>>(parts);
  scanC_kernel<<<NBLK_SCAN, 256, 0, stream>>>(offs, parts);
  scatter_kernel<<<6250, 256, 0, stream>>>(dst, offs, attr, attrS, dsts);

  hipMemsetAsync(aggr, 0, (size_t)N_NODES * 128 * sizeof(int), stream);
  prep_kernel<<<616, 256, 0, stream>>>(Wm2, Wm3, Wu1, Wu2, Wu3, W2bf, W3bf, Wu1p, Wu2p, Wu3p);

  edge_kernel<<<N_EDGES / 128, 256, 0, stream>>>(attrS, dsts, Wm1, bm1, W2bf, bm2, W3bf,
                                                 bm3, aggr);
  node_kernel<<<(N_NODES + 31) / 32, 256, 0, stream>>>(x, aggr, lng, lnb, Wu1p, bu1, Wu2p, bu2,
                                                       Wu3p, bu3, out);
}

// Round 9
// 640.580 us; speedup vs baseline: 1.2215x; 1.1414x over previous
//
#include <hip/hip_runtime.h>

#define N_NODES 100000
#define N_EDGES 1600000
#define STRN 264        // node LDS row stride in ushorts (256 + 8 pad)
#define NBLK_SCAN 391   // ceil(100000/256)

// msg fixed-point scale: aggr accumulates round(v * 2^12) in int32.
// Integer adds are associative -> aggr is EXACTLY order-independent.
#define MSG_SCALE 4096.0f
#define MSG_INV   0.000244140625f

typedef __attribute__((ext_vector_type(4))) float floatx4;
typedef __attribute__((ext_vector_type(8))) __bf16 bf16x8;
typedef __attribute__((ext_vector_type(8))) unsigned short ushort8;
typedef __attribute__((ext_vector_type(4))) unsigned short ushort4v;

// ---- ws layout (bytes) ----
#define WS_AGGR   0ull                        // 51,200,000  int32 [N][128] (fixed-point)
#define WS_COUNTS 51200000ull                 // 400,384     int[100096]
#define WS_OFFS   51600384ull                 // 400,384
#define WS_PART   52000768ull                 // 2,048       int[512]
#define WS_DSTS   52002816ull                 // 6,400,000   int[E] (dst-sorted)
#define WS_ATTRS  58402816ull                 // 32,000,000  fp32 [E][5] (dst-sorted)
#define WS_W2     90402816ull                 // Wm2 bf16 [128][128]
#define WS_W3     (WS_W2 + 32768ull)
#define WS_WU1    (WS_W3 + 32768ull)          // Wu1 bf16 padded [224][256]
#define WS_WU2    (WS_WU1 + 114688ull)        // Wu2 bf16 padded [192][224]
#define WS_WU3    (WS_WU2 + 86016ull)         // Wu3 bf16 padded [128][192]
#define WS_W1     (WS_WU3 + 49152ull)         // Wm1 bf16 padded [128][32] (K 5->32 zeros)

__device__ __forceinline__ unsigned short tobf(float f) {
  return __builtin_bit_cast(unsigned short, (__bf16)f);
}

__device__ __forceinline__ float leaky(float v) { return fmaxf(v, 0.01f * v); }

// XOR-swizzled ushort index into a [128 rows][128 ch] bf16 LDS tile.
__device__ __forceinline__ int swz(int row, int ch) {
  return row * 128 + (ch ^ ((row & 7) << 3));
}

// int32 msg slab index: [128 edges][16 ch].
__device__ __forceinline__ int msw(int e, int ch) {
  return e * 16 + (ch ^ (((e >> 1) & 3) << 2));
}

// bank-staggered dst index: window q's 32 ints sit 8 banks apart
__device__ __forceinline__ int dsw(int e) { return e + ((e >> 5) << 3); }

// ---------------- weight prep: fp32 -> bf16 (+ zero padding) ----------------
__global__ void prep_kernel(const float* __restrict__ Wm1, const float* __restrict__ Wm2,
                            const float* __restrict__ Wm3,
                            const float* __restrict__ Wu1, const float* __restrict__ Wu2,
                            const float* __restrict__ Wu3,
                            unsigned short* __restrict__ o1b,
                            unsigned short* __restrict__ o2, unsigned short* __restrict__ o3,
                            unsigned short* __restrict__ o1p, unsigned short* __restrict__ o2p,
                            unsigned short* __restrict__ o3p) {
  int i = blockIdx.x * 256 + threadIdx.x;
  if (i < 16384) {
    o2[i] = tobf(Wm2[i]);
  } else if (i < 32768) {
    int j = i - 16384; o3[j] = tobf(Wm3[j]);
  } else if (i < 32768 + 57344) {            // Wu1 pad [214][256] -> [224][256]
    int j = i - 32768; int n = j >> 8, k = j & 255;
    o1p[j] = (n < 214) ? tobf(Wu1[n * 256 + k]) : (unsigned short)0;
  } else if (i < 90112 + 43008) {            // Wu2 pad [172][214] -> [192][224]
    int j = i - 90112; int n = j / 224, k = j - n * 224;
    o2p[j] = (n < 172 && k < 214) ? tobf(Wu2[n * 214 + k]) : (unsigned short)0;
  } else if (i < 133120 + 24576) {           // Wu3 pad [128][172] -> [128][192]
    int j = i - 133120; int n = j / 192, k = j - n * 192;
    o3p[j] = (k < 172) ? tobf(Wu3[n * 172 + k]) : (unsigned short)0;
  } else if (i < 157696 + 4096) {            // Wm1 pad [128][5] -> [128][32]
    int j = i - 157696; int n = j >> 5, k = j & 31;
    o1b[j] = (k < 5) ? tobf(Wm1[n * 5 + k]) : (unsigned short)0;
  }
}

// ---------------- counting sort of edges by dst ----------------
__global__ void hist_kernel(const int* __restrict__ dst, int* __restrict__ counts) {
  int e = blockIdx.x * 256 + threadIdx.x;
  if (e < N_EDGES) atomicAdd(&counts[dst[e]], 1);
}

__global__ void scanA_kernel(const int* __restrict__ counts, int* __restrict__ offs,
                             int* __restrict__ partials) {
  __shared__ int tmp[256];
  const int t = threadIdx.x;
  const int i = blockIdx.x * 256 + t;
  int v = (i < N_NODES) ? counts[i] : 0;
  tmp[t] = v;
  __syncthreads();
  for (int off = 1; off < 256; off <<= 1) {
    int a = (t >= off) ? tmp[t - off] : 0;
    __syncthreads();
    tmp[t] += a;
    __syncthreads();
  }
  if (i < N_NODES) offs[i] = tmp[t] - v;  // exclusive
  if (t == 255) partials[blockIdx.x] = tmp[255];
}

__global__ void scanB_kernel(int* __restrict__ partials) {
  __shared__ int tmp[512];
  const int t = threadIdx.x;
  int v = (t < NBLK_SCAN) ? partials[t] : 0;
  tmp[t] = v;
  __syncthreads();
  for (int off = 1; off < 512; off <<= 1) {
    int a = (t >= off) ? tmp[t - off] : 0;
    __syncthreads();
    tmp[t] += a;
    __syncthreads();
  }
  if (t < NBLK_SCAN) partials[t] = tmp[t] - v;  // exclusive
}

__global__ void scanC_kernel(int* __restrict__ offs, const int* __restrict__ partials) {
  int i = blockIdx.x * 256 + threadIdx.x;
  if (i < N_NODES) offs[i] += partials[blockIdx.x];
}

// scatter: reorder the edge PAYLOAD (attr rows + dst) into dst-sorted order.
// Within-dst permutation is nondeterministic, but downstream int32 aggregation
// is exactly order-independent, so the final output doesn't depend on it.
__global__ void scatter_kernel(const int* __restrict__ dst, int* __restrict__ offs,
                               const float* __restrict__ attr,
                               float* __restrict__ attrS, int* __restrict__ dsts) {
  int e = blockIdx.x * 256 + threadIdx.x;
  if (e < N_EDGES) {
    int d = dst[e];
    int p = atomicAdd(&offs[d], 1);
    dsts[p] = d;
    const float* a = attr + (size_t)e * 5;
    float a0 = a[0], a1 = a[1], a2 = a[2], a3 = a[3], a4 = a[4];
    float* o = attrS + (size_t)p * 5;
    o[0] = a0; o[1] = a1; o[2] = a2; o[3] = a3; o[4] = a4;
  }
}

// ---------------- edge kernel ----------------
// ALL THREE layers on the matrix pipe (layer 1: K padded 5->32 with zeros).
// Swapped-operand MFMA: A = weight rows prefetched, B = activations from LDS.
// sMsg holds int32 fixed-point (cvt in the parallel epilogue, not the serial
// walk); dst fetch via bank-staggered sDst. LDS 33.8KB -> 4 blocks/CU.
__global__ __launch_bounds__(256, 4) void edge_kernel(
    const float* __restrict__ attrS, const int* __restrict__ dsts,
    const unsigned short* __restrict__ W1bf, const float* __restrict__ bm1,
    const unsigned short* __restrict__ W2bf, const float* __restrict__ bm2,
    const unsigned short* __restrict__ W3bf, const float* __restrict__ bm3,
    int* __restrict__ aggr) {
  __shared__ __align__(16) char smem[33792];
  unsigned short* sH = (unsigned short*)(void*)smem;     // [0,32768): h tile bf16, swizzled
  unsigned short* sAttrB = sH;                           // overlay: [128][40] bf16 (10240B)
  int* sMsgI = (int*)(void*)smem;                        // overlay: 4 wave slabs x 2048 int
  int* sDst = (int*)(void*)(smem + 32768);               // 160 ints, bank-staggered

  const int t = threadIdx.x;
  const int wave = t >> 6, lane = t & 63;
  const int col = lane & 15, q = lane >> 4;
  const int wbase = wave * 32;   // this wave's output channels (all layers)
  const long blockEdge = (long)blockIdx.x * 128;

  // ---- stage: attr -> bf16 [128][40] (chunks 0-3 = K32; 5 real + 27 zero) ----
  {
    const int e = t >> 1, half = t & 1;
    ushort8 z;
#pragma unroll
    for (int j = 0; j < 8; j++) z[j] = 0;
    if (half == 0) {
      const float* ar = attrS + (blockEdge + e) * 5;
      ushort8 v = z;
      v[0] = tobf(ar[0]); v[1] = tobf(ar[1]); v[2] = tobf(ar[2]);
      v[3] = tobf(ar[3]); v[4] = tobf(ar[4]);
      *(ushort8*)(void*)&sAttrB[e * 40] = v;
      *(ushort8*)(void*)&sAttrB[e * 40 + 8] = z;
    } else {
      *(ushort8*)(void*)&sAttrB[e * 40 + 16] = z;
      *(ushort8*)(void*)&sAttrB[e * 40 + 24] = z;
    }
    if (t < 128) sDst[dsw(t)] = dsts[blockEdge + t];
  }
  __syncthreads();

  floatx4 acc[2][8];

  // ---- layer 1 MFMA: A = W1 rows [wbase,wbase+32), B = attr (K=32, 1 ks) ----
  {
    bf16x8 w1f[2];
#pragma unroll
    for (int i = 0; i < 2; i++)
      w1f[i] = *(const bf16x8*)(const void*)&W1bf[(wbase + i * 16 + col) * 32 + q * 8];
#pragma unroll
    for (int i = 0; i < 2; i++)
#pragma unroll
      for (int j = 0; j < 8; j++) acc[i][j] = (floatx4){0.f, 0.f, 0.f, 0.f};
#pragma unroll
    for (int et = 0; et < 8; et++) {
      bf16x8 b = *(const bf16x8*)(const void*)&sAttrB[(et * 16 + col) * 40 + q * 8];
      acc[0][et] = __builtin_amdgcn_mfma_f32_16x16x32_bf16(w1f[0], b, acc[0][et], 0, 0, 0);
      acc[1][et] = __builtin_amdgcn_mfma_f32_16x16x32_bf16(w1f[1], b, acc[1][et], 0, 0, 0);
    }
  }
  __syncthreads();  // all sAttrB reads done; region becomes sH

  // ---- layer-1 epilogue: h1 = leaky(acc + bm1) -> sH, packed b64 ----
  {
    float4 blo = *(const float4*)&bm1[wbase + q * 4];
    float4 bhi = *(const float4*)&bm1[wbase + 16 + q * 4];
#pragma unroll
    for (int et = 0; et < 8; et++) {
      const int e = et * 16 + col;
      ushort4v plo, phi;
#pragma unroll
      for (int r = 0; r < 4; r++) {
        plo[r] = tobf(leaky(acc[0][et][r] + ((const float*)&blo)[r]));
        phi[r] = tobf(leaky(acc[1][et][r] + ((const float*)&bhi)[r]));
      }
      *(ushort4v*)(void*)&sH[swz(e, wbase + q * 4)] = plo;
      *(ushort4v*)(void*)&sH[swz(e, wbase + 16 + q * 4)] = phi;
    }
  }
  __syncthreads();  // h1 complete before layer-2 reads

  // ---- layer 2: A = W2 rows, prefetched; B = h1 from LDS ----
  {
    bf16x8 w2f[2][4];
#pragma unroll
    for (int i = 0; i < 2; i++)
#pragma unroll
      for (int ks = 0; ks < 4; ks++)
        w2f[i][ks] = *(const bf16x8*)(const void*)
            &W2bf[(wbase + i * 16 + col) * 128 + ks * 32 + q * 8];
#pragma unroll
    for (int i = 0; i < 2; i++)
#pragma unroll
      for (int j = 0; j < 8; j++) acc[i][j] = (floatx4){0.f, 0.f, 0.f, 0.f};
#pragma unroll
    for (int ks = 0; ks < 4; ks++) {
      const int kk = ks * 32 + q * 8;
#pragma unroll
      for (int et = 0; et < 8; et++) {
        bf16x8 hb = *(const bf16x8*)(const void*)&sH[swz(et * 16 + col, kk)];
        acc[0][et] = __builtin_amdgcn_mfma_f32_16x16x32_bf16(w2f[0][ks], hb, acc[0][et], 0, 0, 0);
        acc[1][et] = __builtin_amdgcn_mfma_f32_16x16x32_bf16(w2f[1][ks], hb, acc[1][et], 0, 0, 0);
      }
    }
  }
  __syncthreads();  // all layer-2 reads done before h2 overwrites sH

  // ---- layer-2 epilogue: h2 -> sH, packed b64 ----
  {
    float4 blo = *(const float4*)&bm2[wbase + q * 4];
    float4 bhi = *(const float4*)&bm2[wbase + 16 + q * 4];
#pragma unroll
    for (int et = 0; et < 8; et++) {
      const int e = et * 16 + col;
      ushort4v plo, phi;
#pragma unroll
      for (int r = 0; r < 4; r++) {
        plo[r] = tobf(leaky(acc[0][et][r] + ((const float*)&blo)[r]));
        phi[r] = tobf(leaky(acc[1][et][r] + ((const float*)&bhi)[r]));
      }
      *(ushort4v*)(void*)&sH[swz(e, wbase + q * 4)] = plo;
      *(ushort4v*)(void*)&sH[swz(e, wbase + 16 + q * 4)] = phi;
    }
  }
  __syncthreads();  // h2 complete before layer-3 reads

  // ---- layer 3: A = W3 rows, prefetched; B = h2 from LDS ----
  {
    bf16x8 w3f[2][4];
#pragma unroll
    for (int i = 0; i < 2; i++)
#pragma unroll
      for (int ks = 0; ks < 4; ks++)
        w3f[i][ks] = *(const bf16x8*)(const void*)
            &W3bf[(wbase + i * 16 + col) * 128 + ks * 32 + q * 8];
#pragma unroll
    for (int i = 0; i < 2; i++)
#pragma unroll
      for (int j = 0; j < 8; j++) acc[i][j] = (floatx4){0.f, 0.f, 0.f, 0.f};
#pragma unroll
    for (int ks = 0; ks < 4; ks++) {
      const int kk = ks * 32 + q * 8;
#pragma unroll
      for (int et = 0; et < 8; et++) {
        bf16x8 hb = *(const bf16x8*)(const void*)&sH[swz(et * 16 + col, kk)];
        acc[0][et] = __builtin_amdgcn_mfma_f32_16x16x32_bf16(w3f[0][ks], hb, acc[0][et], 0, 0, 0);
        acc[1][et] = __builtin_amdgcn_mfma_f32_16x16x32_bf16(w3f[1][ks], hb, acc[1][et], 0, 0, 0);
      }
    }
  }
  __syncthreads();  // all sH reads done; smem becomes per-wave int slabs

  // ---- two 16-channel chunks: msg -> int32 slab (cvt HERE, in parallel;
  //      packed b128), then pure-int segment walk ----
  const int wslab = wave * 2048;
#pragma unroll
  for (int c = 0; c < 2; c++) {
    float4 b3 = *(const float4*)&bm3[wbase + c * 16 + q * 4];
#pragma unroll
    for (int et = 0; et < 8; et++) {
      const int e = et * 16 + col;
      int4 p;
      p.x = __float2int_rn((acc[c][et][0] + b3.x) * MSG_SCALE);
      p.y = __float2int_rn((acc[c][et][1] + b3.y) * MSG_SCALE);
      p.z = __float2int_rn((acc[c][et][2] + b3.z) * MSG_SCALE);
      p.w = __float2int_rn((acc[c][et][3] + b3.w) * MSG_SCALE);
      *(int4*)(void*)&sMsgI[wslab + msw(e, q * 4)] = p;
    }
    asm volatile("s_waitcnt lgkmcnt(0)" ::: "memory");  // wave-local slab visible

    // lane -> (ch = lane&15, window = q of 32 edges); serial chain = read+add
    const int ch = col;
    const int chG = wbase + c * 16 + ch;
    const int e0 = q * 32;
    int accv = 0;
    int dprev = sDst[dsw(e0)];
#pragma unroll 8
    for (int it = 0; it < 32; it++) {
      const int e = e0 + it;
      int d = sDst[dsw(e)];
      int iv = sMsgI[wslab + msw(e, ch)];
      if (d != dprev) {
        atomicAdd(&aggr[(size_t)dprev * 128 + chG], accv);
        accv = 0;
        dprev = d;
      }
      accv += iv;
    }
    atomicAdd(&aggr[(size_t)dprev * 128 + chG], accv);
  }
}

// ---------------- node layer (swapped-operand MFMA, 64-node blocks; r4-verified) ----
template <int TILES, int CT, int KST, bool FINAL>
__device__ __forceinline__ void layer_node_sw(unsigned short* __restrict__ sX,
                                              const unsigned short* __restrict__ W,
                                              const float* __restrict__ bias, int biasLim,
                                              int wave, int lane, int nodeGBase,
                                              float* __restrict__ out) {
  const int col = lane & 15, q = lane >> 4;
  const int K = KST * 32;
  floatx4 acc[CT][4];
#pragma unroll
  for (int c = 0; c < CT; c++)
#pragma unroll
    for (int n = 0; n < 4; n++) acc[c][n] = (floatx4){0.f, 0.f, 0.f, 0.f};

#pragma unroll
  for (int ks = 0; ks < KST; ks++) {
    const int kk = ks * 32 + q * 8;
    bf16x8 a[CT];
#pragma unroll
    for (int c = 0; c < CT; c++) {
      const int tile = wave + 4 * c;
      const int tc = (tile < TILES) ? tile : 0;  // always defined, always in-bounds
      a[c] = *(const bf16x8*)(const void*)&W[(tc * 16 + col) * K + kk];
    }
    bf16x8 b[4];
#pragma unroll
    for (int n = 0; n < 4; n++)
      b[n] = *(const bf16x8*)(const void*)&sX[(n * 16 + col) * STRN + kk];
#pragma unroll
    for (int c = 0; c < CT; c++) {
      if (wave + 4 * c < TILES) {
#pragma unroll
        for (int n = 0; n < 4; n++)
          acc[c][n] = __builtin_amdgcn_mfma_f32_16x16x32_bf16(a[c], b[n], acc[c][n], 0, 0, 0);
      }
    }
  }
  __syncthreads();  // all waves done reading sX before epilogue overwrites

#pragma unroll
  for (int c = 0; c < CT; c++) {
    const int tile = wave + 4 * c;
    if (tile < TILES) {
      float bv[4];
#pragma unroll
      for (int r = 0; r < 4; r++) {
        const int ch = tile * 16 + q * 4 + r;
        bv[r] = (ch < biasLim) ? bias[ch] : 0.f;
      }
#pragma unroll
      for (int n = 0; n < 4; n++) {
        const int node = n * 16 + col;
        if (!FINAL) {
          ushort4v p;
#pragma unroll
          for (int r = 0; r < 4; r++) p[r] = tobf(leaky(acc[c][n][r] + bv[r]));
          *(ushort4v*)(void*)&sX[node * STRN + tile * 16 + q * 4] = p;
        } else {
          const long ng = (long)nodeGBase + node;
          if (ng < N_NODES) {
            float4 p = make_float4(acc[c][n][0] + bv[0], acc[c][n][1] + bv[1],
                                   acc[c][n][2] + bv[2], acc[c][n][3] + bv[3]);
            *(float4*)(void*)&out[ng * 128 + tile * 16 + q * 4] = p;
          }
        }
      }
    }
  }
  if (!FINAL) __syncthreads();  // writes visible before next layer reads
}

// ---------------- node kernel: LN(concat) + MLP, 64 nodes/block ----------------
// aggr arrives as int32 fixed-point; conversion iv*MSG_INV is deterministic.
__global__ __launch_bounds__(256, 4) void node_kernel(
    const float* __restrict__ x, const int* __restrict__ aggr,
    const float* __restrict__ lng, const float* __restrict__ lnb,
    const unsigned short* __restrict__ Wu1p, const float* __restrict__ bu1,
    const unsigned short* __restrict__ Wu2p, const float* __restrict__ bu2,
    const unsigned short* __restrict__ Wu3p, const float* __restrict__ bu3,
    float* __restrict__ out) {
  __shared__ unsigned short sX[64 * STRN];  // [node][c] bf16, padded stride
  __shared__ float sG[256], sB[256];
  const int t = threadIdx.x;
  const int wave = t >> 6, lane = t & 63;
  sG[t] = lng[t];
  sB[t] = lnb[t];

  // LayerNorm over cat=[x,aggr] (fp32). 4 threads per node.
  const int nl = t >> 2;
  const int part = t & 3;
  const long nodeG = (long)blockIdx.x * 64 + nl;
  const bool valid = nodeG < N_NODES;
  const float* srcF = x + nodeG * 128 + part * 64;
  const int* srcI = aggr + nodeG * 128 + (part - 2) * 64;
  float s = 0.f, ss = 0.f;
  if (valid) {
#pragma unroll
    for (int i = 0; i < 16; i++) {
      float4 a;
      if (part < 2) {
        a = *(const float4*)(srcF + i * 4);
      } else {
        int4 iv = *(const int4*)(srcI + i * 4);
        a = make_float4(iv.x * MSG_INV, iv.y * MSG_INV, iv.z * MSG_INV, iv.w * MSG_INV);
      }
      s += a.x + a.y + a.z + a.w;
      ss += a.x * a.x + a.y * a.y + a.z * a.z + a.w * a.w;
    }
  }
  s += __shfl_xor(s, 1); s += __shfl_xor(s, 2);
  ss += __shfl_xor(ss, 1); ss += __shfl_xor(ss, 2);
  const float mean = s * (1.f / 256.f);
  const float var = ss * (1.f / 256.f) - mean * mean;
  const float rstd = rsqrtf(var + 1e-5f);
  __syncthreads();  // sG/sB visible
  if (valid) {
    const int cb = part * 64;
#pragma unroll
    for (int i = 0; i < 16; i++) {
      float4 a;
      if (part < 2) {
        a = *(const float4*)(srcF + i * 4);
      } else {
        int4 iv = *(const int4*)(srcI + i * 4);
        a = make_float4(iv.x * MSG_INV, iv.y * MSG_INV, iv.z * MSG_INV, iv.w * MSG_INV);
      }
      int c = cb + i * 4;
      ushort4v p;
      p[0] = tobf((a.x - mean) * rstd * sG[c + 0] + sB[c + 0]);
      p[1] = tobf((a.y - mean) * rstd * sG[c + 1] + sB[c + 1]);
      p[2] = tobf((a.z - mean) * rstd * sG[c + 2] + sB[c + 2]);
      p[3] = tobf((a.w - mean) * rstd * sG[c + 3] + sB[c + 3]);
      *(ushort4v*)(void*)&sX[nl * STRN + c] = p;
    }
  }
  __syncthreads();

  const int nodeGBase = blockIdx.x * 64;
  layer_node_sw<14, 4, 8, false>(sX, Wu1p, bu1, 214, wave, lane, nodeGBase, nullptr);
  layer_node_sw<12, 3, 7, false>(sX, Wu2p, bu2, 172, wave, lane, nodeGBase, nullptr);
  layer_node_sw<8, 2, 6, true>(sX, Wu3p, bu3, 128, wave, lane, nodeGBase, out);
}

// ---------------- launch ----------------
extern "C" void kernel_launch(void* const* d_in, const int* in_sizes, int n_in,
                              void* d_out, int out_size, void* d_ws, size_t ws_size,
                              hipStream_t stream) {
  const float* x    = (const float*)d_in[0];
  const int*   eidx = (const int*)d_in[1];
  const float* attr = (const float*)d_in[2];
  const float* Wm1  = (const float*)d_in[3];
  const float* bm1  = (const float*)d_in[4];
  const float* Wm2  = (const float*)d_in[5];
  const float* bm2  = (const float*)d_in[6];
  const float* Wm3  = (const float*)d_in[7];
  const float* bm3  = (const float*)d_in[8];
  const float* lng  = (const float*)d_in[9];
  const float* lnb  = (const float*)d_in[10];
  const float* Wu1  = (const float*)d_in[11];
  const float* bu1  = (const float*)d_in[12];
  const float* Wu2  = (const float*)d_in[13];
  const float* bu2  = (const float*)d_in[14];
  const float* Wu3  = (const float*)d_in[15];
  const float* bu3  = (const float*)d_in[16];
  float* out = (float*)d_out;

  char* ws = (char*)d_ws;
  int* aggr    = (int*)(ws + WS_AGGR);
  int* counts  = (int*)(ws + WS_COUNTS);
  int* offs    = (int*)(ws + WS_OFFS);
  int* parts   = (int*)(ws + WS_PART);
  int* dsts    = (int*)(ws + WS_DSTS);
  float* attrS = (float*)(ws + WS_ATTRS);
  unsigned short* W2bf = (unsigned short*)(ws + WS_W2);
  unsigned short* W3bf = (unsigned short*)(ws + WS_W3);
  unsigned short* Wu1p = (unsigned short*)(ws + WS_WU1);
  unsigned short* Wu2p = (unsigned short*)(ws + WS_WU2);
  unsigned short* Wu3p = (unsigned short*)(ws + WS_WU3);
  unsigned short* W1bf = (unsigned short*)(ws + WS_W1);

  const int* dst = eidx + N_EDGES;  // edge_index[1]

  // counting sort of edges by dst (payload reorder: attrS + dsts)
  hipMemsetAsync(counts, 0, 400384, stream);
  hist_kernel<<<6250, 256, 0, stream>>>(dst, counts);
  scanA_kernel<<<NBLK_SCAN, 256, 0, stream>>>(counts, offs, parts);
  scanB_kernel<<<1, 512, 0, stream>>>(parts);
  scanC_kernel<<<NBLK_SCAN, 256, 0, stream>>>(offs, parts);
  scatter_kernel<<<6250, 256, 0, stream>>>(dst, offs, attr, attrS, dsts);

  hipMemsetAsync(aggr, 0, (size_t)N_NODES * 128 * sizeof(int), stream);
  prep_kernel<<<632, 256, 0, stream>>>(Wm1, Wm2, Wm3, Wu1, Wu2, Wu3,
                                       W1bf, W2bf, W3bf, Wu1p, Wu2p, Wu3p);

  edge_kernel<<<N_EDGES / 128, 256, 0, stream>>>(attrS, dsts, W1bf, bm1, W2bf, bm2, W3bf,
                                                 bm3, aggr);
  node_kernel<<<(N_NODES + 63) / 64, 256, 0, stream>>>(x, aggr, lng, lnb, Wu1p, bu1, Wu2p, bu2,
                                                       Wu3p, bu3, out);
}

// Round 10
// 634.559 us; speedup vs baseline: 1.2331x; 1.0095x over previous
//
#include <hip/hip_runtime.h>

#define N_NODES 100000
#define N_EDGES 1600000
#define STRN 264        // node LDS row stride in ushorts (256 + 8 pad)
#define NBLK_SCAN 391   // ceil(100000/256)

// msg fixed-point scale: aggr accumulates round(v * 2^12) in int32.
// Integer adds are associative -> aggr is EXACTLY order-independent.
#define MSG_SCALE 4096.0f
#define MSG_INV   0.000244140625f

typedef __attribute__((ext_vector_type(4))) float floatx4;
typedef __attribute__((ext_vector_type(8))) __bf16 bf16x8;
typedef __attribute__((ext_vector_type(8))) unsigned short ushort8;
typedef __attribute__((ext_vector_type(4))) unsigned short ushort4v;

// ---- ws layout (bytes) ----
#define WS_AGGR   0ull                        // 51,200,000  int32 [N][128] (fixed-point)
                                              //   doubles as rank[E] (6.4MB) before memset
#define WS_COUNTS 51200000ull                 // 400,384     int[100096]
#define WS_OFFS   51600384ull                 // 400,384
#define WS_PART   52000768ull                 // 2,048       int[512]
#define WS_DSTS   52002816ull                 // 6,400,000   int[E] (dst-sorted)
#define WS_ATTRS  58402816ull                 // 32,000,000  fp32 [E][5] (dst-sorted)
#define WS_W2     90402816ull                 // Wm2 bf16 [128][128]
#define WS_W3     (WS_W2 + 32768ull)
#define WS_WU1    (WS_W3 + 32768ull)          // Wu1 bf16 padded [224][256]
#define WS_WU2    (WS_WU1 + 114688ull)        // Wu2 bf16 padded [192][224]
#define WS_WU3    (WS_WU2 + 86016ull)         // Wu3 bf16 padded [128][192]
#define WS_W1     (WS_WU3 + 49152ull)         // Wm1 bf16 padded [128][32] (K 5->32 zeros)

__device__ __forceinline__ unsigned short tobf(float f) {
  return __builtin_bit_cast(unsigned short, (__bf16)f);
}

__device__ __forceinline__ float leaky(float v) { return fmaxf(v, 0.01f * v); }

// XOR-swizzled ushort index into a [128 rows][128 ch] bf16 LDS tile.
__device__ __forceinline__ int swz(int row, int ch) {
  return row * 128 + (ch ^ ((row & 7) << 3));
}

// int32 msg slab index: [128 edges][16 ch]. Caller adds the per-window shift
// (window*8 ints) so the walk's four windows land on staggered banks.
__device__ __forceinline__ int msw(int e, int ch) {
  return e * 16 + (ch ^ (((e >> 1) & 3) << 2));
}

// bank-staggered dst index: window q's 32 ints sit 8 banks apart
__device__ __forceinline__ int dsw(int e) { return e + ((e >> 5) << 3); }

// ---------------- weight prep: fp32 -> bf16 (+ zero padding) ----------------
__global__ void prep_kernel(const float* __restrict__ Wm1, const float* __restrict__ Wm2,
                            const float* __restrict__ Wm3,
                            const float* __restrict__ Wu1, const float* __restrict__ Wu2,
                            const float* __restrict__ Wu3,
                            unsigned short* __restrict__ o1b,
                            unsigned short* __restrict__ o2, unsigned short* __restrict__ o3,
                            unsigned short* __restrict__ o1p, unsigned short* __restrict__ o2p,
                            unsigned short* __restrict__ o3p) {
  int i = blockIdx.x * 256 + threadIdx.x;
  if (i < 16384) {
    o2[i] = tobf(Wm2[i]);
  } else if (i < 32768) {
    int j = i - 16384; o3[j] = tobf(Wm3[j]);
  } else if (i < 32768 + 57344) {            // Wu1 pad [214][256] -> [224][256]
    int j = i - 32768; int n = j >> 8, k = j & 255;
    o1p[j] = (n < 214) ? tobf(Wu1[n * 256 + k]) : (unsigned short)0;
  } else if (i < 90112 + 43008) {            // Wu2 pad [172][214] -> [192][224]
    int j = i - 90112; int n = j / 224, k = j - n * 224;
    o2p[j] = (n < 172 && k < 214) ? tobf(Wu2[n * 214 + k]) : (unsigned short)0;
  } else if (i < 133120 + 24576) {           // Wu3 pad [128][172] -> [128][192]
    int j = i - 133120; int n = j / 192, k = j - n * 192;
    o3p[j] = (k < 172) ? tobf(Wu3[n * 172 + k]) : (unsigned short)0;
  } else if (i < 157696 + 4096) {            // Wm1 pad [128][5] -> [128][32]
    int j = i - 157696; int n = j >> 5, k = j & 31;
    o1b[j] = (k < 5) ? tobf(Wm1[n * 5 + k]) : (unsigned short)0;
  }
}

// ---------------- counting sort of edges by dst ----------------
// hist also RECORDS each edge's within-dst rank (coalesced write) so the
// scatter pass needs no atomics at all.
__global__ void hist_kernel(const int* __restrict__ dst, int* __restrict__ counts,
                            int* __restrict__ rank) {
  int e = blockIdx.x * 256 + threadIdx.x;
  if (e < N_EDGES) rank[e] = atomicAdd(&counts[dst[e]], 1);
}

__global__ void scanA_kernel(const int* __restrict__ counts, int* __restrict__ offs,
                             int* __restrict__ partials) {
  __shared__ int tmp[256];
  const int t = threadIdx.x;
  const int i = blockIdx.x * 256 + t;
  int v = (i < N_NODES) ? counts[i] : 0;
  tmp[t] = v;
  __syncthreads();
  for (int off = 1; off < 256; off <<= 1) {
    int a = (t >= off) ? tmp[t - off] : 0;
    __syncthreads();
    tmp[t] += a;
    __syncthreads();
  }
  if (i < N_NODES) offs[i] = tmp[t] - v;  // exclusive (within block)
  if (t == 255) partials[blockIdx.x] = tmp[255];
}

__global__ void scanB_kernel(int* __restrict__ partials) {
  __shared__ int tmp[512];
  const int t = threadIdx.x;
  int v = (t < NBLK_SCAN) ? partials[t] : 0;
  tmp[t] = v;
  __syncthreads();
  for (int off = 1; off < 512; off <<= 1) {
    int a = (t >= off) ? tmp[t - off] : 0;
    __syncthreads();
    tmp[t] += a;
    __syncthreads();
  }
  if (t < NBLK_SCAN) partials[t] = tmp[t] - v;  // exclusive
}

// scatter (atomic-free): p = block-local exclusive offs + block prefix + rank.
// scanC is fused via parts[d>>8]. Within-dst permutation differs from the old
// atomic scheme -- irrelevant: downstream int32 aggregation is order-exact.
__global__ void scatter_kernel(const int* __restrict__ dst, const int* __restrict__ offs,
                               const int* __restrict__ parts, const int* __restrict__ rank,
                               const float* __restrict__ attr,
                               float* __restrict__ attrS, int* __restrict__ dsts) {
  int e = blockIdx.x * 256 + threadIdx.x;
  if (e < N_EDGES) {
    int d = dst[e];
    int p = offs[d] + parts[d >> 8] + rank[e];
    dsts[p] = d;
    const float* a = attr + (size_t)e * 5;
    float a0 = a[0], a1 = a[1], a2 = a[2], a3 = a[3], a4 = a[4];
    float* o = attrS + (size_t)p * 5;
    o[0] = a0; o[1] = a1; o[2] = a2; o[3] = a3; o[4] = a4;
  }
}

// ---------------- edge kernel ----------------
// ALL THREE layers on the matrix pipe (layer 1: K padded 5->32 with zeros).
// Swapped-operand MFMA: A = weight rows prefetched, B = activations from LDS.
// sMsgI int32 slabs now window-shifted (w*8 ints, slab stride 2080) so the
// serial walk reads are 2-way bank-free with ZERO extra VALU in the chain.
__global__ __launch_bounds__(256, 4) void edge_kernel(
    const float* __restrict__ attrS, const int* __restrict__ dsts,
    const unsigned short* __restrict__ W1bf, const float* __restrict__ bm1,
    const unsigned short* __restrict__ W2bf, const float* __restrict__ bm2,
    const unsigned short* __restrict__ W3bf, const float* __restrict__ bm3,
    int* __restrict__ aggr) {
  __shared__ __align__(16) char smem[33920];
  unsigned short* sH = (unsigned short*)(void*)smem;     // [0,32768): h tile bf16, swizzled
  unsigned short* sAttrB = sH;                           // overlay: [128][40] bf16 (10240B)
  int* sMsgI = (int*)(void*)smem;                        // overlay: 4 slabs x 2080 int
  int* sDst = (int*)(void*)(smem + 33280);               // 160 ints, bank-staggered

  const int t = threadIdx.x;
  const int wave = t >> 6, lane = t & 63;
  const int col = lane & 15, q = lane >> 4;
  const int wbase = wave * 32;   // this wave's output channels (all layers)
  const long blockEdge = (long)blockIdx.x * 128;

  // ---- stage: attr -> bf16 [128][40] (chunks 0-3 = K32; 5 real + 27 zero) ----
  {
    const int e = t >> 1, half = t & 1;
    ushort8 z;
#pragma unroll
    for (int j = 0; j < 8; j++) z[j] = 0;
    if (half == 0) {
      const float* ar = attrS + (blockEdge + e) * 5;
      ushort8 v = z;
      v[0] = tobf(ar[0]); v[1] = tobf(ar[1]); v[2] = tobf(ar[2]);
      v[3] = tobf(ar[3]); v[4] = tobf(ar[4]);
      *(ushort8*)(void*)&sAttrB[e * 40] = v;
      *(ushort8*)(void*)&sAttrB[e * 40 + 8] = z;
    } else {
      *(ushort8*)(void*)&sAttrB[e * 40 + 16] = z;
      *(ushort8*)(void*)&sAttrB[e * 40 + 24] = z;
    }
    if (t < 128) sDst[dsw(t)] = dsts[blockEdge + t];
  }
  __syncthreads();

  floatx4 acc[2][8];

  // ---- layer 1 MFMA: A = W1 rows [wbase,wbase+32), B = attr (K=32, 1 ks) ----
  {
    bf16x8 w1f[2];
#pragma unroll
    for (int i = 0; i < 2; i++)
      w1f[i] = *(const bf16x8*)(const void*)&W1bf[(wbase + i * 16 + col) * 32 + q * 8];
#pragma unroll
    for (int i = 0; i < 2; i++)
#pragma unroll
      for (int j = 0; j < 8; j++) acc[i][j] = (floatx4){0.f, 0.f, 0.f, 0.f};
#pragma unroll
    for (int et = 0; et < 8; et++) {
      bf16x8 b = *(const bf16x8*)(const void*)&sAttrB[(et * 16 + col) * 40 + q * 8];
      acc[0][et] = __builtin_amdgcn_mfma_f32_16x16x32_bf16(w1f[0], b, acc[0][et], 0, 0, 0);
      acc[1][et] = __builtin_amdgcn_mfma_f32_16x16x32_bf16(w1f[1], b, acc[1][et], 0, 0, 0);
    }
  }
  __syncthreads();  // all sAttrB reads done; region becomes sH

  // ---- layer-1 epilogue: h1 = leaky(acc + bm1) -> sH, packed b64 ----
  {
    float4 blo = *(const float4*)&bm1[wbase + q * 4];
    float4 bhi = *(const float4*)&bm1[wbase + 16 + q * 4];
#pragma unroll
    for (int et = 0; et < 8; et++) {
      const int e = et * 16 + col;
      ushort4v plo, phi;
#pragma unroll
      for (int r = 0; r < 4; r++) {
        plo[r] = tobf(leaky(acc[0][et][r] + ((const float*)&blo)[r]));
        phi[r] = tobf(leaky(acc[1][et][r] + ((const float*)&bhi)[r]));
      }
      *(ushort4v*)(void*)&sH[swz(e, wbase + q * 4)] = plo;
      *(ushort4v*)(void*)&sH[swz(e, wbase + 16 + q * 4)] = phi;
    }
  }
  __syncthreads();  // h1 complete before layer-2 reads

  // ---- layer 2: A = W2 rows, prefetched; B = h1 from LDS ----
  {
    bf16x8 w2f[2][4];
#pragma unroll
    for (int i = 0; i < 2; i++)
#pragma unroll
      for (int ks = 0; ks < 4; ks++)
        w2f[i][ks] = *(const bf16x8*)(const void*)
            &W2bf[(wbase + i * 16 + col) * 128 + ks * 32 + q * 8];
#pragma unroll
    for (int i = 0; i < 2; i++)
#pragma unroll
      for (int j = 0; j < 8; j++) acc[i][j] = (floatx4){0.f, 0.f, 0.f, 0.f};
#pragma unroll
    for (int ks = 0; ks < 4; ks++) {
      const int kk = ks * 32 + q * 8;
#pragma unroll
      for (int et = 0; et < 8; et++) {
        bf16x8 hb = *(const bf16x8*)(const void*)&sH[swz(et * 16 + col, kk)];
        acc[0][et] = __builtin_amdgcn_mfma_f32_16x16x32_bf16(w2f[0][ks], hb, acc[0][et], 0, 0, 0);
        acc[1][et] = __builtin_amdgcn_mfma_f32_16x16x32_bf16(w2f[1][ks], hb, acc[1][et], 0, 0, 0);
      }
    }
  }
  __syncthreads();  // all layer-2 reads done before h2 overwrites sH

  // ---- layer-2 epilogue: h2 -> sH, packed b64 ----
  {
    float4 blo = *(const float4*)&bm2[wbase + q * 4];
    float4 bhi = *(const float4*)&bm2[wbase + 16 + q * 4];
#pragma unroll
    for (int et = 0; et < 8; et++) {
      const int e = et * 16 + col;
      ushort4v plo, phi;
#pragma unroll
      for (int r = 0; r < 4; r++) {
        plo[r] = tobf(leaky(acc[0][et][r] + ((const float*)&blo)[r]));
        phi[r] = tobf(leaky(acc[1][et][r] + ((const float*)&bhi)[r]));
      }
      *(ushort4v*)(void*)&sH[swz(e, wbase + q * 4)] = plo;
      *(ushort4v*)(void*)&sH[swz(e, wbase + 16 + q * 4)] = phi;
    }
  }
  __syncthreads();  // h2 complete before layer-3 reads

  // ---- layer 3: A = W3 rows, prefetched; B = h2 from LDS ----
  {
    bf16x8 w3f[2][4];
#pragma unroll
    for (int i = 0; i < 2; i++)
#pragma unroll
      for (int ks = 0; ks < 4; ks++)
        w3f[i][ks] = *(const bf16x8*)(const void*)
            &W3bf[(wbase + i * 16 + col) * 128 + ks * 32 + q * 8];
#pragma unroll
    for (int i = 0; i < 2; i++)
#pragma unroll
      for (int j = 0; j < 8; j++) acc[i][j] = (floatx4){0.f, 0.f, 0.f, 0.f};
#pragma unroll
    for (int ks = 0; ks < 4; ks++) {
      const int kk = ks * 32 + q * 8;
#pragma unroll
      for (int et = 0; et < 8; et++) {
        bf16x8 hb = *(const bf16x8*)(const void*)&sH[swz(et * 16 + col, kk)];
        acc[0][et] = __builtin_amdgcn_mfma_f32_16x16x32_bf16(w3f[0][ks], hb, acc[0][et], 0, 0, 0);
        acc[1][et] = __builtin_amdgcn_mfma_f32_16x16x32_bf16(w3f[1][ks], hb, acc[1][et], 0, 0, 0);
      }
    }
  }
  __syncthreads();  // all sH reads done; smem becomes per-wave int slabs

  // ---- two 16-channel chunks: msg -> int32 slab (cvt in parallel, b128,
  //      window-shifted), then pure-int segment walk (2-way bank-free) ----
  const int wslab = wave * 2080;
#pragma unroll
  for (int c = 0; c < 2; c++) {
    float4 b3 = *(const float4*)&bm3[wbase + c * 16 + q * 4];
#pragma unroll
    for (int et = 0; et < 8; et++) {
      const int e = et * 16 + col;
      int4 p;
      p.x = __float2int_rn((acc[c][et][0] + b3.x) * MSG_SCALE);
      p.y = __float2int_rn((acc[c][et][1] + b3.y) * MSG_SCALE);
      p.z = __float2int_rn((acc[c][et][2] + b3.z) * MSG_SCALE);
      p.w = __float2int_rn((acc[c][et][3] + b3.w) * MSG_SCALE);
      *(int4*)(void*)&sMsgI[wslab + (et >> 1) * 8 + msw(e, q * 4)] = p;  // (et>>1)==e>>5
    }
    asm volatile("s_waitcnt lgkmcnt(0)" ::: "memory");  // wave-local slab visible

    // lane -> (ch = lane&15, window = q of 32 edges); serial chain = read+add
    const int ch = col;
    const int chG = wbase + c * 16 + ch;
    const int e0 = q * 32;
    const int wbW = wslab + q * 8;  // window shift folded into base once
    int accv = 0;
    int dprev = sDst[dsw(e0)];
#pragma unroll 8
    for (int it = 0; it < 32; it++) {
      const int e = e0 + it;
      int d = sDst[dsw(e)];
      int iv = sMsgI[wbW + msw(e, ch)];
      if (d != dprev) {
        atomicAdd(&aggr[(size_t)dprev * 128 + chG], accv);
        accv = 0;
        dprev = d;
      }
      accv += iv;
    }
    atomicAdd(&aggr[(size_t)dprev * 128 + chG], accv);
  }
}

// ---------------- node layer (swapped-operand MFMA, 64-node blocks; verified) ----
template <int TILES, int CT, int KST, bool FINAL>
__device__ __forceinline__ void layer_node_sw(unsigned short* __restrict__ sX,
                                              const unsigned short* __restrict__ W,
                                              const float* __restrict__ bias, int biasLim,
                                              int wave, int lane, int nodeGBase,
                                              float* __restrict__ out) {
  const int col = lane & 15, q = lane >> 4;
  const int K = KST * 32;
  floatx4 acc[CT][4];
#pragma unroll
  for (int c = 0; c < CT; c++)
#pragma unroll
    for (int n = 0; n < 4; n++) acc[c][n] = (floatx4){0.f, 0.f, 0.f, 0.f};

#pragma unroll
  for (int ks = 0; ks < KST; ks++) {
    const int kk = ks * 32 + q * 8;
    bf16x8 a[CT];
#pragma unroll
    for (int c = 0; c < CT; c++) {
      const int tile = wave + 4 * c;
      const int tc = (tile < TILES) ? tile : 0;  // always defined, always in-bounds
      a[c] = *(const bf16x8*)(const void*)&W[(tc * 16 + col) * K + kk];
    }
    bf16x8 b[4];
#pragma unroll
    for (int n = 0; n < 4; n++)
      b[n] = *(const bf16x8*)(const void*)&sX[(n * 16 + col) * STRN + kk];
#pragma unroll
    for (int c = 0; c < CT; c++) {
      if (wave + 4 * c < TILES) {
#pragma unroll
        for (int n = 0; n < 4; n++)
          acc[c][n] = __builtin_amdgcn_mfma_f32_16x16x32_bf16(a[c], b[n], acc[c][n], 0, 0, 0);
      }
    }
  }
  __syncthreads();  // all waves done reading sX before epilogue overwrites

#pragma unroll
  for (int c = 0; c < CT; c++) {
    const int tile = wave + 4 * c;
    if (tile < TILES) {
      float bv[4];
#pragma unroll
      for (int r = 0; r < 4; r++) {
        const int ch = tile * 16 + q * 4 + r;
        bv[r] = (ch < biasLim) ? bias[ch] : 0.f;
      }
#pragma unroll
      for (int n = 0; n < 4; n++) {
        const int node = n * 16 + col;
        if (!FINAL) {
          ushort4v p;
#pragma unroll
          for (int r = 0; r < 4; r++) p[r] = tobf(leaky(acc[c][n][r] + bv[r]));
          *(ushort4v*)(void*)&sX[node * STRN + tile * 16 + q * 4] = p;
        } else {
          const long ng = (long)nodeGBase + node;
          if (ng < N_NODES) {
            float4 p = make_float4(acc[c][n][0] + bv[0], acc[c][n][1] + bv[1],
                                   acc[c][n][2] + bv[2], acc[c][n][3] + bv[3]);
            *(float4*)(void*)&out[ng * 128 + tile * 16 + q * 4] = p;
          }
        }
      }
    }
  }
  if (!FINAL) __syncthreads();  // writes visible before next layer reads
}

// ---------------- node kernel: LN(concat) + MLP, 64 nodes/block ----------------
// aggr arrives as int32 fixed-point; conversion iv*MSG_INV is deterministic.
__global__ __launch_bounds__(256, 4) void node_kernel(
    const float* __restrict__ x, const int* __restrict__ aggr,
    const float* __restrict__ lng, const float* __restrict__ lnb,
    const unsigned short* __restrict__ Wu1p, const float* __restrict__ bu1,
    const unsigned short* __restrict__ Wu2p, const float* __restrict__ bu2,
    const unsigned short* __restrict__ Wu3p, const float* __restrict__ bu3,
    float* __restrict__ out) {
  __shared__ unsigned short sX[64 * STRN];  // [node][c] bf16, padded stride
  __shared__ float sG[256], sB[256];
  const int t = threadIdx.x;
  const int wave = t >> 6, lane = t & 63;
  sG[t] = lng[t];
  sB[t] = lnb[t];

  // LayerNorm over cat=[x,aggr] (fp32). 4 threads per node.
  const int nl = t >> 2;
  const int part = t & 3;
  const long nodeG = (long)blockIdx.x * 64 + nl;
  const bool valid = nodeG < N_NODES;
  const float* srcF = x + nodeG * 128 + part * 64;
  const int* srcI = aggr + nodeG * 128 + (part - 2) * 64;
  float s = 0.f, ss = 0.f;
  if (valid) {
#pragma unroll
    for (int i = 0; i < 16; i++) {
      float4 a;
      if (part < 2) {
        a = *(const float4*)(srcF + i * 4);
      } else {
        int4 iv = *(const int4*)(srcI + i * 4);
        a = make_float4(iv.x * MSG_INV, iv.y * MSG_INV, iv.z * MSG_INV, iv.w * MSG_INV);
      }
      s += a.x + a.y + a.z + a.w;
      ss += a.x * a.x + a.y * a.y + a.z * a.z + a.w * a.w;
    }
  }
  s += __shfl_xor(s, 1); s += __shfl_xor(s, 2);
  ss += __shfl_xor(ss, 1); ss += __shfl_xor(ss, 2);
  const float mean = s * (1.f / 256.f);
  const float var = ss * (1.f / 256.f) - mean * mean;
  const float rstd = rsqrtf(var + 1e-5f);
  __syncthreads();  // sG/sB visible
  if (valid) {
    const int cb = part * 64;
#pragma unroll
    for (int i = 0; i < 16; i++) {
      float4 a;
      if (part < 2) {
        a = *(const float4*)(srcF + i * 4);
      } else {
        int4 iv = *(const int4*)(srcI + i * 4);
        a = make_float4(iv.x * MSG_INV, iv.y * MSG_INV, iv.z * MSG_INV, iv.w * MSG_INV);
      }
      int c = cb + i * 4;
      ushort4v p;
      p[0] = tobf((a.x - mean) * rstd * sG[c + 0] + sB[c + 0]);
      p[1] = tobf((a.y - mean) * rstd * sG[c + 1] + sB[c + 1]);
      p[2] = tobf((a.z - mean) * rstd * sG[c + 2] + sB[c + 2]);
      p[3] = tobf((a.w - mean) * rstd * sG[c + 3] + sB[c + 3]);
      *(ushort4v*)(void*)&sX[nl * STRN + c] = p;
    }
  }
  __syncthreads();

  const int nodeGBase = blockIdx.x * 64;
  layer_node_sw<14, 4, 8, false>(sX, Wu1p, bu1, 214, wave, lane, nodeGBase, nullptr);
  layer_node_sw<12, 3, 7, false>(sX, Wu2p, bu2, 172, wave, lane, nodeGBase, nullptr);
  layer_node_sw<8, 2, 6, true>(sX, Wu3p, bu3, 128, wave, lane, nodeGBase, out);
}

// ---------------- launch ----------------
extern "C" void kernel_launch(void* const* d_in, const int* in_sizes, int n_in,
                              void* d_out, int out_size, void* d_ws, size_t ws_size,
                              hipStream_t stream) {
  const float* x    = (const float*)d_in[0];
  const int*   eidx = (const int*)d_in[1];
  const float* attr = (const float*)d_in[2];
  const float* Wm1  = (const float*)d_in[3];
  const float* bm1  = (const float*)d_in[4];
  const float* Wm2  = (const float*)d_in[5];
  const float* bm2  = (const float*)d_in[6];
  const float* Wm3  = (const float*)d_in[7];
  const float* bm3  = (const float*)d_in[8];
  const float* lng  = (const float*)d_in[9];
  const float* lnb  = (const float*)d_in[10];
  const float* Wu1  = (const float*)d_in[11];
  const float* bu1  = (const float*)d_in[12];
  const float* Wu2  = (const float*)d_in[13];
  const float* bu2  = (const float*)d_in[14];
  const float* Wu3  = (const float*)d_in[15];
  const float* bu3  = (const float*)d_in[16];
  float* out = (float*)d_out;

  char* ws = (char*)d_ws;
  int* aggr    = (int*)(ws + WS_AGGR);
  int* rank    = (int*)(ws + WS_AGGR);   // aliased: used before aggr memset
  int* counts  = (int*)(ws + WS_COUNTS);
  int* offs    = (int*)(ws + WS_OFFS);
  int* parts   = (int*)(ws + WS_PART);
  int* dsts    = (int*)(ws + WS_DSTS);
  float* attrS = (float*)(ws + WS_ATTRS);
  unsigned short* W2bf = (unsigned short*)(ws + WS_W2);
  unsigned short* W3bf = (unsigned short*)(ws + WS_W3);
  unsigned short* Wu1p = (unsigned short*)(ws + WS_WU1);
  unsigned short* Wu2p = (unsigned short*)(ws + WS_WU2);
  unsigned short* Wu3p = (unsigned short*)(ws + WS_WU3);
  unsigned short* W1bf = (unsigned short*)(ws + WS_W1);

  const int* dst = eidx + N_EDGES;  // edge_index[1]

  // counting sort of edges by dst. hist records ranks; scatter is atomic-free
  // (scanC fused via parts[d>>8]). rank lives in the aggr buffer, which is
  // memset only AFTER scatter has consumed it.
  hipMemsetAsync(counts, 0, 400384, stream);
  hist_kernel<<<6250, 256, 0, stream>>>(dst, counts, rank);
  scanA_kernel<<<NBLK_SCAN, 256, 0, stream>>>(counts, offs, parts);
  scanB_kernel<<<1, 512, 0, stream>>>(parts);
  scatter_kernel<<<6250, 256, 0, stream>>>(dst, offs, parts, rank, attr, attrS, dsts);

  hipMemsetAsync(aggr, 0, (size_t)N_NODES * 128 * sizeof(int), stream);
  prep_kernel<<<632, 256, 0, stream>>>(Wm1, Wm2, Wm3, Wu1, Wu2, Wu3,
                                       W1bf, W2bf, W3bf, Wu1p, Wu2p, Wu3p);

  edge_kernel<<<N_EDGES / 128, 256, 0, stream>>>(attrS, dsts, W1bf, bm1, W2bf, bm2, W3bf,
                                                 bm3, aggr);
  node_kernel<<<(N_NODES + 63) / 64, 256, 0, stream>>>(x, aggr, lng, lnb, Wu1p, bu1, Wu2p, bu2,
                                                       Wu3p, bu3, out);
}

// Round 11
// 594.055 us; speedup vs baseline: 1.3172x; 1.0682x over previous
//
#include <hip/hip_runtime.h>

#define N_NODES 100000
#define N_EDGES 1600000
#define STRN 264        // node LDS row stride in ushorts (256 + 8 pad)
#define NBLK_SCAN 391   // ceil(100000/256)

// msg fixed-point scale: aggr accumulates round(v * 2^12) in int32.
// Integer adds are associative -> aggr is EXACTLY order-independent.
#define MSG_SCALE 4096.0f
#define MSG_INV   0.000244140625f

typedef __attribute__((ext_vector_type(4))) float floatx4;
typedef __attribute__((ext_vector_type(8))) __bf16 bf16x8;
typedef __attribute__((ext_vector_type(8))) unsigned short ushort8;
typedef __attribute__((ext_vector_type(4))) unsigned short ushort4v;

// ---- ws layout (bytes) ----
#define WS_AGGR   0ull                        // 51,200,000  int32 [N][128] (fixed-point)
                                              //   doubles as rank[E] (6.4MB) before memset
#define WS_COUNTS 51200000ull                 // 400,384     int[100096]
#define WS_OFFS   51600384ull                 // 400,384
#define WS_PART   52000768ull                 // 2,048       int[512]
#define WS_DSTS   52002816ull                 // 6,400,000   int[E] (dst-sorted)
#define WS_ATTRS  58402816ull                 // 25,600,000  ushort [E][8] bf16 records
#define WS_W2     90402816ull                 // Wm2 bf16 [128][128]
#define WS_W3     (WS_W2 + 32768ull)
#define WS_WU1    (WS_W3 + 32768ull)          // Wu1 bf16 padded [224][256]
#define WS_WU2    (WS_WU1 + 114688ull)        // Wu2 bf16 padded [192][224]
#define WS_WU3    (WS_WU2 + 86016ull)         // Wu3 bf16 padded [128][192]
#define WS_W1     (WS_WU3 + 49152ull)         // Wm1 bf16 padded [128][32] (K 5->32 zeros)

__device__ __forceinline__ unsigned short tobf(float f) {
  return __builtin_bit_cast(unsigned short, (__bf16)f);
}

__device__ __forceinline__ float leaky(float v) { return fmaxf(v, 0.01f * v); }

// XOR-swizzled ushort index into a [128 rows][128 ch] bf16 LDS tile.
__device__ __forceinline__ int swz(int row, int ch) {
  return row * 128 + (ch ^ ((row & 7) << 3));
}

// ---------------- weight prep: fp32 -> bf16 (+ zero padding) ----------------
__global__ void prep_kernel(const float* __restrict__ Wm1, const float* __restrict__ Wm2,
                            const float* __restrict__ Wm3,
                            const float* __restrict__ Wu1, const float* __restrict__ Wu2,
                            const float* __restrict__ Wu3,
                            unsigned short* __restrict__ o1b,
                            unsigned short* __restrict__ o2, unsigned short* __restrict__ o3,
                            unsigned short* __restrict__ o1p, unsigned short* __restrict__ o2p,
                            unsigned short* __restrict__ o3p) {
  int i = blockIdx.x * 256 + threadIdx.x;
  if (i < 16384) {
    o2[i] = tobf(Wm2[i]);
  } else if (i < 32768) {
    int j = i - 16384; o3[j] = tobf(Wm3[j]);
  } else if (i < 32768 + 57344) {            // Wu1 pad [214][256] -> [224][256]
    int j = i - 32768; int n = j >> 8, k = j & 255;
    o1p[j] = (n < 214) ? tobf(Wu1[n * 256 + k]) : (unsigned short)0;
  } else if (i < 90112 + 43008) {            // Wu2 pad [172][214] -> [192][224]
    int j = i - 90112; int n = j / 224, k = j - n * 224;
    o2p[j] = (n < 172 && k < 214) ? tobf(Wu2[n * 214 + k]) : (unsigned short)0;
  } else if (i < 133120 + 24576) {           // Wu3 pad [128][172] -> [128][192]
    int j = i - 133120; int n = j / 192, k = j - n * 192;
    o3p[j] = (k < 172) ? tobf(Wu3[n * 172 + k]) : (unsigned short)0;
  } else if (i < 157696 + 4096) {            // Wm1 pad [128][5] -> [128][32]
    int j = i - 157696; int n = j >> 5, k = j & 31;
    o1b[j] = (k < 5) ? tobf(Wm1[n * 5 + k]) : (unsigned short)0;
  }
}

// ---------------- counting sort of edges by dst ----------------
// hist records each edge's within-dst rank (coalesced write) so the scatter
// pass needs no atomics at all.
__global__ void hist_kernel(const int* __restrict__ dst, int* __restrict__ counts,
                            int* __restrict__ rank) {
  int e = blockIdx.x * 256 + threadIdx.x;
  if (e < N_EDGES) rank[e] = atomicAdd(&counts[dst[e]], 1);
}

__global__ void scanA_kernel(const int* __restrict__ counts, int* __restrict__ offs,
                             int* __restrict__ partials) {
  __shared__ int tmp[256];
  const int t = threadIdx.x;
  const int i = blockIdx.x * 256 + t;
  int v = (i < N_NODES) ? counts[i] : 0;
  tmp[t] = v;
  __syncthreads();
  for (int off = 1; off < 256; off <<= 1) {
    int a = (t >= off) ? tmp[t - off] : 0;
    __syncthreads();
    tmp[t] += a;
    __syncthreads();
  }
  if (i < N_NODES) offs[i] = tmp[t] - v;  // exclusive (within block)
  if (t == 255) partials[blockIdx.x] = tmp[255];
}

__global__ void scanB_kernel(int* __restrict__ partials) {
  __shared__ int tmp[512];
  const int t = threadIdx.x;
  int v = (t < NBLK_SCAN) ? partials[t] : 0;
  tmp[t] = v;
  __syncthreads();
  for (int off = 1; off < 512; off <<= 1) {
    int a = (t >= off) ? tmp[t - off] : 0;
    __syncthreads();
    tmp[t] += a;
    __syncthreads();
  }
  if (t < NBLK_SCAN) partials[t] = tmp[t] - v;  // exclusive
}

// scatter (atomic-free): p = block-local exclusive offs + block prefix + rank.
// Writes a 16B bf16 record {a0..a4, 0,0,0} (single scattered store) — the
// tobf conversion moves here from the edge stage (same function, identical
// bits). Downstream int32 aggregation keeps the output order-independent.
__global__ void scatter_kernel(const int* __restrict__ dst, const int* __restrict__ offs,
                               const int* __restrict__ parts, const int* __restrict__ rank,
                               const float* __restrict__ attr,
                               unsigned short* __restrict__ attrB, int* __restrict__ dsts) {
  int e = blockIdx.x * 256 + threadIdx.x;
  if (e < N_EDGES) {
    int d = dst[e];
    int p = offs[d] + parts[d >> 8] + rank[e];
    dsts[p] = d;
    const float* a = attr + (size_t)e * 5;
    ushort8 v;
    v[0] = tobf(a[0]); v[1] = tobf(a[1]); v[2] = tobf(a[2]);
    v[3] = tobf(a[3]); v[4] = tobf(a[4]);
    v[5] = 0; v[6] = 0; v[7] = 0;
    *(ushort8*)(void*)&attrB[(size_t)p * 8] = v;
  }
}

// ---------------- edge kernel ----------------
// ALL THREE layers on the matrix pipe. Swapped-operand MFMA: A = weight rows
// prefetched, B = activations from LDS. New walk: wave owns an edge WINDOW,
// lane = channel -> d is wave-uniform (scalar branch, no divergence), window
// dsts preloaded in one register (readlane, no LDS in serial chain), segment
// atomics are 64-lane coalesced 256B. Msg slab [128][64] int (32KB overlay),
// 2 channel-chunks. LDS 33.3KB -> 4 blocks/CU.
__global__ __launch_bounds__(256, 4) void edge_kernel(
    const unsigned short* __restrict__ attrB, const int* __restrict__ dsts,
    const unsigned short* __restrict__ W1bf, const float* __restrict__ bm1,
    const unsigned short* __restrict__ W2bf, const float* __restrict__ bm2,
    const unsigned short* __restrict__ W3bf, const float* __restrict__ bm3,
    int* __restrict__ aggr) {
  __shared__ __align__(16) char smem[33280];
  unsigned short* sH = (unsigned short*)(void*)smem;     // [0,32768): h tile bf16, swizzled
  unsigned short* sAttrB = sH;                           // overlay: [128][40] bf16 (10240B)
  int* sMsgI = (int*)(void*)smem;                        // overlay: [128][64] int (32768B)
  int* sDst = (int*)(void*)(smem + 32768);               // 128 ints

  const int t = threadIdx.x;
  const int wave = t >> 6, lane = t & 63;
  const int col = lane & 15, q = lane >> 4;
  const int wbase = wave * 32;   // this wave's output channels (all layers)
  const long blockEdge = (long)blockIdx.x * 128;

  // ---- stage: records are already bf16 with slots 5-7 zeroed; copy + zero tail ----
  if (t < 128) {
    *(ushort8*)(void*)&sAttrB[t * 40] =
        *(const ushort8*)(const void*)&attrB[(blockEdge + t) * 8];
    sDst[t] = dsts[blockEdge + t];
  }
  {
    ushort8 z;
#pragma unroll
    for (int j = 0; j < 8; j++) z[j] = 0;
#pragma unroll
    for (int i = 0; i < 2; i++) {
      const int idx = i * 256 + t;           // 512 zero-stores: rows' [8,40)
      const int row = idx >> 2, part = idx & 3;
      *(ushort8*)(void*)&sAttrB[row * 40 + 8 + part * 8] = z;
    }
  }
  __syncthreads();

  floatx4 acc[2][8];

  // ---- layer 1 MFMA: A = W1 rows [wbase,wbase+32), B = attr (K=32, 1 ks) ----
  {
    bf16x8 w1f[2];
#pragma unroll
    for (int i = 0; i < 2; i++)
      w1f[i] = *(const bf16x8*)(const void*)&W1bf[(wbase + i * 16 + col) * 32 + q * 8];
#pragma unroll
    for (int i = 0; i < 2; i++)
#pragma unroll
      for (int j = 0; j < 8; j++) acc[i][j] = (floatx4){0.f, 0.f, 0.f, 0.f};
#pragma unroll
    for (int et = 0; et < 8; et++) {
      bf16x8 b = *(const bf16x8*)(const void*)&sAttrB[(et * 16 + col) * 40 + q * 8];
      acc[0][et] = __builtin_amdgcn_mfma_f32_16x16x32_bf16(w1f[0], b, acc[0][et], 0, 0, 0);
      acc[1][et] = __builtin_amdgcn_mfma_f32_16x16x32_bf16(w1f[1], b, acc[1][et], 0, 0, 0);
    }
  }
  __syncthreads();  // all sAttrB reads done; region becomes sH

  // ---- layer-1 epilogue: h1 = leaky(acc + bm1) -> sH, packed b64 ----
  {
    float4 blo = *(const float4*)&bm1[wbase + q * 4];
    float4 bhi = *(const float4*)&bm1[wbase + 16 + q * 4];
#pragma unroll
    for (int et = 0; et < 8; et++) {
      const int e = et * 16 + col;
      ushort4v plo, phi;
#pragma unroll
      for (int r = 0; r < 4; r++) {
        plo[r] = tobf(leaky(acc[0][et][r] + ((const float*)&blo)[r]));
        phi[r] = tobf(leaky(acc[1][et][r] + ((const float*)&bhi)[r]));
      }
      *(ushort4v*)(void*)&sH[swz(e, wbase + q * 4)] = plo;
      *(ushort4v*)(void*)&sH[swz(e, wbase + 16 + q * 4)] = phi;
    }
  }
  __syncthreads();  // h1 complete before layer-2 reads

  // ---- layer 2: A = W2 rows, prefetched; B = h1 from LDS ----
  {
    bf16x8 w2f[2][4];
#pragma unroll
    for (int i = 0; i < 2; i++)
#pragma unroll
      for (int ks = 0; ks < 4; ks++)
        w2f[i][ks] = *(const bf16x8*)(const void*)
            &W2bf[(wbase + i * 16 + col) * 128 + ks * 32 + q * 8];
#pragma unroll
    for (int i = 0; i < 2; i++)
#pragma unroll
      for (int j = 0; j < 8; j++) acc[i][j] = (floatx4){0.f, 0.f, 0.f, 0.f};
#pragma unroll
    for (int ks = 0; ks < 4; ks++) {
      const int kk = ks * 32 + q * 8;
#pragma unroll
      for (int et = 0; et < 8; et++) {
        bf16x8 hb = *(const bf16x8*)(const void*)&sH[swz(et * 16 + col, kk)];
        acc[0][et] = __builtin_amdgcn_mfma_f32_16x16x32_bf16(w2f[0][ks], hb, acc[0][et], 0, 0, 0);
        acc[1][et] = __builtin_amdgcn_mfma_f32_16x16x32_bf16(w2f[1][ks], hb, acc[1][et], 0, 0, 0);
      }
    }
  }
  __syncthreads();  // all layer-2 reads done before h2 overwrites sH

  // ---- layer-2 epilogue: h2 -> sH, packed b64 ----
  {
    float4 blo = *(const float4*)&bm2[wbase + q * 4];
    float4 bhi = *(const float4*)&bm2[wbase + 16 + q * 4];
#pragma unroll
    for (int et = 0; et < 8; et++) {
      const int e = et * 16 + col;
      ushort4v plo, phi;
#pragma unroll
      for (int r = 0; r < 4; r++) {
        plo[r] = tobf(leaky(acc[0][et][r] + ((const float*)&blo)[r]));
        phi[r] = tobf(leaky(acc[1][et][r] + ((const float*)&bhi)[r]));
      }
      *(ushort4v*)(void*)&sH[swz(e, wbase + q * 4)] = plo;
      *(ushort4v*)(void*)&sH[swz(e, wbase + 16 + q * 4)] = phi;
    }
  }
  __syncthreads();  // h2 complete before layer-3 reads

  // ---- layer 3: A = W3 rows, prefetched; B = h2 from LDS ----
  {
    bf16x8 w3f[2][4];
#pragma unroll
    for (int i = 0; i < 2; i++)
#pragma unroll
      for (int ks = 0; ks < 4; ks++)
        w3f[i][ks] = *(const bf16x8*)(const void*)
            &W3bf[(wbase + i * 16 + col) * 128 + ks * 32 + q * 8];
#pragma unroll
    for (int i = 0; i < 2; i++)
#pragma unroll
      for (int j = 0; j < 8; j++) acc[i][j] = (floatx4){0.f, 0.f, 0.f, 0.f};
#pragma unroll
    for (int ks = 0; ks < 4; ks++) {
      const int kk = ks * 32 + q * 8;
#pragma unroll
      for (int et = 0; et < 8; et++) {
        bf16x8 hb = *(const bf16x8*)(const void*)&sH[swz(et * 16 + col, kk)];
        acc[0][et] = __builtin_amdgcn_mfma_f32_16x16x32_bf16(w3f[0][ks], hb, acc[0][et], 0, 0, 0);
        acc[1][et] = __builtin_amdgcn_mfma_f32_16x16x32_bf16(w3f[1][ks], hb, acc[1][et], 0, 0, 0);
      }
    }
  }
  __syncthreads();  // all sH reads done; smem becomes the [128][64] int slab

  // ---- preload this wave's 32 window dsts into one register (lane l -> dst
  //      of edge wave*32 + (l&31)); serial chain then uses readlane only ----
  const int dmy = sDst[wave * 32 + (lane & 31)];

  // ---- two 64-channel chunks: owning waves write msg (int32, swizzled),
  //      then ALL waves walk their 32-edge window with lane = channel ----
#pragma unroll
  for (int c = 0; c < 2; c++) {
    if ((wave >> 1) == c) {
#pragma unroll
      for (int ci = 0; ci < 2; ci++) {
        float4 b3 = *(const float4*)&bm3[wbase + ci * 16 + q * 4];
        const int cb = (wbase + ci * 16 + q * 4) & 63;
#pragma unroll
        for (int et = 0; et < 8; et++) {
          const int e = et * 16 + col;
          int4 p;
          p.x = __float2int_rn((acc[ci][et][0] + b3.x) * MSG_SCALE);
          p.y = __float2int_rn((acc[ci][et][1] + b3.y) * MSG_SCALE);
          p.z = __float2int_rn((acc[ci][et][2] + b3.z) * MSG_SCALE);
          p.w = __float2int_rn((acc[ci][et][3] + b3.w) * MSG_SCALE);
          *(int4*)(void*)&sMsgI[e * 64 + (cb ^ ((e & 7) << 2))] = p;
        }
      }
    }
    __syncthreads();  // chunk-c msg visible to all waves

    const int e0 = wave * 32;
    const size_t chG = (size_t)c * 64 + lane;
    int accv = 0;
    int dprev = __builtin_amdgcn_readlane(dmy, 0);
#pragma unroll 8
    for (int it = 0; it < 32; it++) {
      const int e = e0 + it;
      const int d = __builtin_amdgcn_readlane(dmy, it);
      const int iv = sMsgI[e * 64 + (lane ^ ((e & 7) << 2))];
      if (d != dprev) {
        atomicAdd(&aggr[(size_t)dprev * 128 + chG], accv);
        accv = 0;
        dprev = d;
      }
      accv += iv;
    }
    atomicAdd(&aggr[(size_t)dprev * 128 + chG], accv);
    if (c == 0) __syncthreads();  // walk-0 done before chunk-1 overwrites slab
  }
}

// ---------------- node layer (swapped-operand MFMA, 64-node blocks; verified) ----
template <int TILES, int CT, int KST, bool FINAL>
__device__ __forceinline__ void layer_node_sw(unsigned short* __restrict__ sX,
                                              const unsigned short* __restrict__ W,
                                              const float* __restrict__ bias, int biasLim,
                                              int wave, int lane, int nodeGBase,
                                              float* __restrict__ out) {
  const int col = lane & 15, q = lane >> 4;
  const int K = KST * 32;
  floatx4 acc[CT][4];
#pragma unroll
  for (int c = 0; c < CT; c++)
#pragma unroll
    for (int n = 0; n < 4; n++) acc[c][n] = (floatx4){0.f, 0.f, 0.f, 0.f};

#pragma unroll
  for (int ks = 0; ks < KST; ks++) {
    const int kk = ks * 32 + q * 8;
    bf16x8 a[CT];
#pragma unroll
    for (int c = 0; c < CT; c++) {
      const int tile = wave + 4 * c;
      const int tc = (tile < TILES) ? tile : 0;  // always defined, always in-bounds
      a[c] = *(const bf16x8*)(const void*)&W[(tc * 16 + col) * K + kk];
    }
    bf16x8 b[4];
#pragma unroll
    for (int n = 0; n < 4; n++)
      b[n] = *(const bf16x8*)(const void*)&sX[(n * 16 + col) * STRN + kk];
#pragma unroll
    for (int c = 0; c < CT; c++) {
      if (wave + 4 * c < TILES) {
#pragma unroll
        for (int n = 0; n < 4; n++)
          acc[c][n] = __builtin_amdgcn_mfma_f32_16x16x32_bf16(a[c], b[n], acc[c][n], 0, 0, 0);
      }
    }
  }
  __syncthreads();  // all waves done reading sX before epilogue overwrites

#pragma unroll
  for (int c = 0; c < CT; c++) {
    const int tile = wave + 4 * c;
    if (tile < TILES) {
      float bv[4];
#pragma unroll
      for (int r = 0; r < 4; r++) {
        const int ch = tile * 16 + q * 4 + r;
        bv[r] = (ch < biasLim) ? bias[ch] : 0.f;
      }
#pragma unroll
      for (int n = 0; n < 4; n++) {
        const int node = n * 16 + col;
        if (!FINAL) {
          ushort4v p;
#pragma unroll
          for (int r = 0; r < 4; r++) p[r] = tobf(leaky(acc[c][n][r] + bv[r]));
          *(ushort4v*)(void*)&sX[node * STRN + tile * 16 + q * 4] = p;
        } else {
          const long ng = (long)nodeGBase + node;
          if (ng < N_NODES) {
            float4 p = make_float4(acc[c][n][0] + bv[0], acc[c][n][1] + bv[1],
                                   acc[c][n][2] + bv[2], acc[c][n][3] + bv[3]);
            *(float4*)(void*)&out[ng * 128 + tile * 16 + q * 4] = p;
          }
        }
      }
    }
  }
  if (!FINAL) __syncthreads();  // writes visible before next layer reads
}

// ---------------- node kernel: LN(concat) + MLP, 64 nodes/block ----------------
// aggr arrives as int32 fixed-point; conversion iv*MSG_INV is deterministic.
__global__ __launch_bounds__(256, 4) void node_kernel(
    const float* __restrict__ x, const int* __restrict__ aggr,
    const float* __restrict__ lng, const float* __restrict__ lnb,
    const unsigned short* __restrict__ Wu1p, const float* __restrict__ bu1,
    const unsigned short* __restrict__ Wu2p, const float* __restrict__ bu2,
    const unsigned short* __restrict__ Wu3p, const float* __restrict__ bu3,
    float* __restrict__ out) {
  __shared__ unsigned short sX[64 * STRN];  // [node][c] bf16, padded stride
  __shared__ float sG[256], sB[256];
  const int t = threadIdx.x;
  const int wave = t >> 6, lane = t & 63;
  sG[t] = lng[t];
  sB[t] = lnb[t];

  // LayerNorm over cat=[x,aggr] (fp32). 4 threads per node.
  const int nl = t >> 2;
  const int part = t & 3;
  const long nodeG = (long)blockIdx.x * 64 + nl;
  const bool valid = nodeG < N_NODES;
  const float* srcF = x + nodeG * 128 + part * 64;
  const int* srcI = aggr + nodeG * 128 + (part - 2) * 64;
  float s = 0.f, ss = 0.f;
  if (valid) {
#pragma unroll
    for (int i = 0; i < 16; i++) {
      float4 a;
      if (part < 2) {
        a = *(const float4*)(srcF + i * 4);
      } else {
        int4 iv = *(const int4*)(srcI + i * 4);
        a = make_float4(iv.x * MSG_INV, iv.y * MSG_INV, iv.z * MSG_INV, iv.w * MSG_INV);
      }
      s += a.x + a.y + a.z + a.w;
      ss += a.x * a.x + a.y * a.y + a.z * a.z + a.w * a.w;
    }
  }
  s += __shfl_xor(s, 1); s += __shfl_xor(s, 2);
  ss += __shfl_xor(ss, 1); ss += __shfl_xor(ss, 2);
  const float mean = s * (1.f / 256.f);
  const float var = ss * (1.f / 256.f) - mean * mean;
  const float rstd = rsqrtf(var + 1e-5f);
  __syncthreads();  // sG/sB visible
  if (valid) {
    const int cb = part * 64;
#pragma unroll
    for (int i = 0; i < 16; i++) {
      float4 a;
      if (part < 2) {
        a = *(const float4*)(srcF + i * 4);
      } else {
        int4 iv = *(const int4*)(srcI + i * 4);
        a = make_float4(iv.x * MSG_INV, iv.y * MSG_INV, iv.z * MSG_INV, iv.w * MSG_INV);
      }
      int c = cb + i * 4;
      ushort4v p;
      p[0] = tobf((a.x - mean) * rstd * sG[c + 0] + sB[c + 0]);
      p[1] = tobf((a.y - mean) * rstd * sG[c + 1] + sB[c + 1]);
      p[2] = tobf((a.z - mean) * rstd * sG[c + 2] + sB[c + 2]);
      p[3] = tobf((a.w - mean) * rstd * sG[c + 3] + sB[c + 3]);
      *(ushort4v*)(void*)&sX[nl * STRN + c] = p;
    }
  }
  __syncthreads();

  const int nodeGBase = blockIdx.x * 64;
  layer_node_sw<14, 4, 8, false>(sX, Wu1p, bu1, 214, wave, lane, nodeGBase, nullptr);
  layer_node_sw<12, 3, 7, false>(sX, Wu2p, bu2, 172, wave, lane, nodeGBase, nullptr);
  layer_node_sw<8, 2, 6, true>(sX, Wu3p, bu3, 128, wave, lane, nodeGBase, out);
}

// ---------------- launch ----------------
extern "C" void kernel_launch(void* const* d_in, const int* in_sizes, int n_in,
                              void* d_out, int out_size, void* d_ws, size_t ws_size,
                              hipStream_t stream) {
  const float* x    = (const float*)d_in[0];
  const int*   eidx = (const int*)d_in[1];
  const float* attr = (const float*)d_in[2];
  const float* Wm1  = (const float*)d_in[3];
  const float* bm1  = (const float*)d_in[4];
  const float* Wm2  = (const float*)d_in[5];
  const float* bm2  = (const float*)d_in[6];
  const float* Wm3  = (const float*)d_in[7];
  const float* bm3  = (const float*)d_in[8];
  const float* lng  = (const float*)d_in[9];
  const float* lnb  = (const float*)d_in[10];
  const float* Wu1  = (const float*)d_in[11];
  const float* bu1  = (const float*)d_in[12];
  const float* Wu2  = (const float*)d_in[13];
  const float* bu2  = (const float*)d_in[14];
  const float* Wu3  = (const float*)d_in[15];
  const float* bu3  = (const float*)d_in[16];
  float* out = (float*)d_out;

  char* ws = (char*)d_ws;
  int* aggr    = (int*)(ws + WS_AGGR);
  int* rank    = (int*)(ws + WS_AGGR);   // aliased: used before aggr memset
  int* counts  = (int*)(ws + WS_COUNTS);
  int* offs    = (int*)(ws + WS_OFFS);
  int* parts   = (int*)(ws + WS_PART);
  int* dsts    = (int*)(ws + WS_DSTS);
  unsigned short* attrB = (unsigned short*)(ws + WS_ATTRS);
  unsigned short* W2bf = (unsigned short*)(ws + WS_W2);
  unsigned short* W3bf = (unsigned short*)(ws + WS_W3);
  unsigned short* Wu1p = (unsigned short*)(ws + WS_WU1);
  unsigned short* Wu2p = (unsigned short*)(ws + WS_WU2);
  unsigned short* Wu3p = (unsigned short*)(ws + WS_WU3);
  unsigned short* W1bf = (unsigned short*)(ws + WS_W1);

  const int* dst = eidx + N_EDGES;  // edge_index[1]

  // counting sort of edges by dst. hist records ranks; scatter is atomic-free
  // (scanC fused via parts[d>>8]) and writes 16B bf16 records. rank lives in
  // the aggr buffer, which is memset only AFTER scatter has consumed it.
  hipMemsetAsync(counts, 0, 400384, stream);
  hist_kernel<<<6250, 256, 0, stream>>>(dst, counts, rank);
  scanA_kernel<<<NBLK_SCAN, 256, 0, stream>>>(counts, offs, parts);
  scanB_kernel<<<1, 512, 0, stream>>>(parts);
  scatter_kernel<<<6250, 256, 0, stream>>>(dst, offs, parts, rank, attr, attrB, dsts);

  hipMemsetAsync(aggr, 0, (size_t)N_NODES * 128 * sizeof(int), stream);
  prep_kernel<<<632, 256, 0, stream>>>(Wm1, Wm2, Wm3, Wu1, Wu2, Wu3,
                                       W1bf, W2bf, W3bf, Wu1p, Wu2p, Wu3p);

  edge_kernel<<<N_EDGES / 128, 256, 0, stream>>>(attrB, dsts, W1bf, bm1, W2bf, bm2, W3bf,
                                                 bm3, aggr);
  node_kernel<<<(N_NODES + 63) / 64, 256, 0, stream>>>(x, aggr, lng, lnb, Wu1p, bu1, Wu2p, bu2,
                                                       Wu3p, bu3, out);
}

// Round 12
// 578.409 us; speedup vs baseline: 1.3528x; 1.0270x over previous
//
#include <hip/hip_runtime.h>

#define N_NODES 100000
#define N_EDGES 1600000
#define STRN 264        // node LDS row stride in ushorts (256 + 8 pad)
#define NBLK_SCAN 391   // ceil(100000/256)

// msg fixed-point scale: aggr accumulates round(v * 2^12) in int32.
// Integer adds are associative -> aggr is EXACTLY order-independent.
#define MSG_SCALE 4096.0f
#define MSG_INV   0.000244140625f

typedef __attribute__((ext_vector_type(4))) float floatx4;
typedef __attribute__((ext_vector_type(8))) __bf16 bf16x8;
typedef __attribute__((ext_vector_type(8))) unsigned short ushort8;
typedef __attribute__((ext_vector_type(4))) unsigned short ushort4v;

// ---- ws layout (bytes) ----
#define WS_AGGR   0ull                        // 51,200,000  int32 [N][128] (fixed-point)
#define WS_COUNTS 51200000ull                 // 400,384     int[100096]
#define WS_OFFS   51600384ull                 // 400,384
#define WS_PART   52000768ull                 // 2,048       int[512]
#define WS_RANK   52002816ull                 // 6,400,000   int[E] within-dst ranks
#define WS_ATTRS  58402816ull                 // 25,600,000  ushort [E][8] records
                                              //   {bf16 a0..a4, 0, d_lo, d_hi} dst-sorted
#define WS_W2     90402816ull                 // Wm2 bf16 [128][128]
#define WS_W3     (WS_W2 + 32768ull)
#define WS_WU1    (WS_W3 + 32768ull)          // Wu1 bf16 padded [224][256]
#define WS_WU2    (WS_WU1 + 114688ull)        // Wu2 bf16 padded [192][224]
#define WS_WU3    (WS_WU2 + 86016ull)         // Wu3 bf16 padded [128][192]
#define WS_W1     (WS_WU3 + 49152ull)         // Wm1 bf16 padded [128][32] (K 5->32 zeros)

__device__ __forceinline__ unsigned short tobf(float f) {
  return __builtin_bit_cast(unsigned short, (__bf16)f);
}

__device__ __forceinline__ float leaky(float v) { return fmaxf(v, 0.01f * v); }

// XOR-swizzled ushort index into a [128 rows][128 ch] bf16 LDS tile.
__device__ __forceinline__ int swz(int row, int ch) {
  return row * 128 + (ch ^ ((row & 7) << 3));
}

// ---------------- fused hist + weight prep ----------------
// hist: records each edge's within-dst rank (coalesced write) so scatter needs
// no atomics. prep (independent, fused to save a launch): fp32 -> bf16 weights.
__global__ void hist_prep_kernel(const int* __restrict__ dst, int* __restrict__ counts,
                                 int* __restrict__ rank,
                                 const float* __restrict__ Wm1, const float* __restrict__ Wm2,
                                 const float* __restrict__ Wm3,
                                 const float* __restrict__ Wu1, const float* __restrict__ Wu2,
                                 const float* __restrict__ Wu3,
                                 unsigned short* __restrict__ o1b,
                                 unsigned short* __restrict__ o2, unsigned short* __restrict__ o3,
                                 unsigned short* __restrict__ o1p, unsigned short* __restrict__ o2p,
                                 unsigned short* __restrict__ o3p) {
  int i = blockIdx.x * 256 + threadIdx.x;
  if (i < N_EDGES) rank[i] = atomicAdd(&counts[dst[i]], 1);
  if (i < 16384) {
    o2[i] = tobf(Wm2[i]);
  } else if (i < 32768) {
    int j = i - 16384; o3[j] = tobf(Wm3[j]);
  } else if (i < 32768 + 57344) {            // Wu1 pad [214][256] -> [224][256]
    int j = i - 32768; int n = j >> 8, k = j & 255;
    o1p[j] = (n < 214) ? tobf(Wu1[n * 256 + k]) : (unsigned short)0;
  } else if (i < 90112 + 43008) {            // Wu2 pad [172][214] -> [192][224]
    int j = i - 90112; int n = j / 224, k = j - n * 224;
    o2p[j] = (n < 172 && k < 214) ? tobf(Wu2[n * 214 + k]) : (unsigned short)0;
  } else if (i < 133120 + 24576) {           // Wu3 pad [128][172] -> [128][192]
    int j = i - 133120; int n = j / 192, k = j - n * 192;
    o3p[j] = (k < 172) ? tobf(Wu3[n * 172 + k]) : (unsigned short)0;
  } else if (i < 157696 + 4096) {            // Wm1 pad [128][5] -> [128][32]
    int j = i - 157696; int n = j >> 5, k = j & 31;
    o1b[j] = (k < 5) ? tobf(Wm1[n * 5 + k]) : (unsigned short)0;
  }
}

__global__ void scanA_kernel(const int* __restrict__ counts, int* __restrict__ offs,
                             int* __restrict__ partials) {
  __shared__ int tmp[256];
  const int t = threadIdx.x;
  const int i = blockIdx.x * 256 + t;
  int v = (i < N_NODES) ? counts[i] : 0;
  tmp[t] = v;
  __syncthreads();
  for (int off = 1; off < 256; off <<= 1) {
    int a = (t >= off) ? tmp[t - off] : 0;
    __syncthreads();
    tmp[t] += a;
    __syncthreads();
  }
  if (i < N_NODES) offs[i] = tmp[t] - v;  // exclusive (within block)
  if (t == 255) partials[blockIdx.x] = tmp[255];
}

__global__ void scanB_kernel(int* __restrict__ partials) {
  __shared__ int tmp[512];
  const int t = threadIdx.x;
  int v = (t < NBLK_SCAN) ? partials[t] : 0;
  tmp[t] = v;
  __syncthreads();
  for (int off = 1; off < 512; off <<= 1) {
    int a = (t >= off) ? tmp[t - off] : 0;
    __syncthreads();
    tmp[t] += a;
    __syncthreads();
  }
  if (t < NBLK_SCAN) partials[t] = tmp[t] - v;  // exclusive
}

// scatter (atomic-free): p = block-local exclusive offs + block prefix + rank.
// Writes ONE 16B record {bf16 a0..a4, 0, d_lo, d_hi} per edge (d embedded ->
// no separate dsts array). Also zeroes this thread's 8-int slice of aggr
// (1.6M x 8 = exactly N*128), replacing the 51.2MB memset launch; edge runs
// after scatter in stream order, so aggr is fully zeroed before any atomic.
__global__ void scatter_kernel(const int* __restrict__ dst, const int* __restrict__ offs,
                               const int* __restrict__ parts, const int* __restrict__ rank,
                               const float* __restrict__ attr,
                               unsigned short* __restrict__ attrB, int* __restrict__ aggr) {
  int e = blockIdx.x * 256 + threadIdx.x;
  if (e < N_EDGES) {
    int d = dst[e];
    int p = offs[d] + parts[d >> 8] + rank[e];
    const float* a = attr + (size_t)e * 5;
    ushort8 v;
    v[0] = tobf(a[0]); v[1] = tobf(a[1]); v[2] = tobf(a[2]);
    v[3] = tobf(a[3]); v[4] = tobf(a[4]);
    v[5] = 0;
    v[6] = (unsigned short)(d & 0xffff);
    v[7] = (unsigned short)(d >> 16);
    *(ushort8*)(void*)&attrB[(size_t)p * 8] = v;
    // fused aggr zeroing (coalesced 32B per thread)
    int4 z = make_int4(0, 0, 0, 0);
    int4* ag = (int4*)(void*)&aggr[(size_t)e * 8];
    ag[0] = z;
    ag[1] = z;
  }
}

// ---------------- edge kernel ----------------
// ALL THREE layers on the matrix pipe. Swapped-operand MFMA: A = weight rows
// prefetched, B = activations from LDS. Records carry d in slots 6-7: stage
// extracts d -> sDst and zeroes those slots before the LDS store, so MFMA
// operands are bit-identical to the zero-padded layout. Walk: wave owns an
// edge window, lane = channel, d wave-uniform via readlane.
__global__ __launch_bounds__(256, 4) void edge_kernel(
    const unsigned short* __restrict__ attrB,
    const unsigned short* __restrict__ W1bf, const float* __restrict__ bm1,
    const unsigned short* __restrict__ W2bf, const float* __restrict__ bm2,
    const unsigned short* __restrict__ W3bf, const float* __restrict__ bm3,
    int* __restrict__ aggr) {
  __shared__ __align__(16) char smem[33280];
  unsigned short* sH = (unsigned short*)(void*)smem;     // [0,32768): h tile bf16, swizzled
  unsigned short* sAttrB = sH;                           // overlay: [128][40] bf16 (10240B)
  int* sMsgI = (int*)(void*)smem;                        // overlay: [128][64] int (32768B)
  int* sDst = (int*)(void*)(smem + 32768);               // 128 ints

  const int t = threadIdx.x;
  const int wave = t >> 6, lane = t & 63;
  const int col = lane & 15, q = lane >> 4;
  const int wbase = wave * 32;   // this wave's output channels (all layers)
  const long blockEdge = (long)blockIdx.x * 128;

  // ---- stage: extract d, zero slots 6-7, copy row; zero tail [8,40) ----
  if (t < 128) {
    ushort8 v = *(const ushort8*)(const void*)&attrB[(blockEdge + t) * 8];
    sDst[t] = (int)v[6] | ((int)v[7] << 16);
    v[6] = 0; v[7] = 0;
    *(ushort8*)(void*)&sAttrB[t * 40] = v;
  }
  {
    ushort8 z;
#pragma unroll
    for (int j = 0; j < 8; j++) z[j] = 0;
#pragma unroll
    for (int i = 0; i < 2; i++) {
      const int idx = i * 256 + t;           // 512 zero-stores: rows' [8,40)
      const int row = idx >> 2, part = idx & 3;
      *(ushort8*)(void*)&sAttrB[row * 40 + 8 + part * 8] = z;
    }
  }
  __syncthreads();

  floatx4 acc[2][8];

  // ---- layer 1 MFMA: A = W1 rows [wbase,wbase+32), B = attr (K=32, 1 ks) ----
  {
    bf16x8 w1f[2];
#pragma unroll
    for (int i = 0; i < 2; i++)
      w1f[i] = *(const bf16x8*)(const void*)&W1bf[(wbase + i * 16 + col) * 32 + q * 8];
#pragma unroll
    for (int i = 0; i < 2; i++)
#pragma unroll
      for (int j = 0; j < 8; j++) acc[i][j] = (floatx4){0.f, 0.f, 0.f, 0.f};
#pragma unroll
    for (int et = 0; et < 8; et++) {
      bf16x8 b = *(const bf16x8*)(const void*)&sAttrB[(et * 16 + col) * 40 + q * 8];
      acc[0][et] = __builtin_amdgcn_mfma_f32_16x16x32_bf16(w1f[0], b, acc[0][et], 0, 0, 0);
      acc[1][et] = __builtin_amdgcn_mfma_f32_16x16x32_bf16(w1f[1], b, acc[1][et], 0, 0, 0);
    }
  }
  __syncthreads();  // all sAttrB reads done; region becomes sH

  // ---- layer-1 epilogue: h1 = leaky(acc + bm1) -> sH, packed b64 ----
  {
    float4 blo = *(const float4*)&bm1[wbase + q * 4];
    float4 bhi = *(const float4*)&bm1[wbase + 16 + q * 4];
#pragma unroll
    for (int et = 0; et < 8; et++) {
      const int e = et * 16 + col;
      ushort4v plo, phi;
#pragma unroll
      for (int r = 0; r < 4; r++) {
        plo[r] = tobf(leaky(acc[0][et][r] + ((const float*)&blo)[r]));
        phi[r] = tobf(leaky(acc[1][et][r] + ((const float*)&bhi)[r]));
      }
      *(ushort4v*)(void*)&sH[swz(e, wbase + q * 4)] = plo;
      *(ushort4v*)(void*)&sH[swz(e, wbase + 16 + q * 4)] = phi;
    }
  }
  __syncthreads();  // h1 complete before layer-2 reads

  // ---- layer 2: A = W2 rows, prefetched; B = h1 from LDS ----
  {
    bf16x8 w2f[2][4];
#pragma unroll
    for (int i = 0; i < 2; i++)
#pragma unroll
      for (int ks = 0; ks < 4; ks++)
        w2f[i][ks] = *(const bf16x8*)(const void*)
            &W2bf[(wbase + i * 16 + col) * 128 + ks * 32 + q * 8];
#pragma unroll
    for (int i = 0; i < 2; i++)
#pragma unroll
      for (int j = 0; j < 8; j++) acc[i][j] = (floatx4){0.f, 0.f, 0.f, 0.f};
#pragma unroll
    for (int ks = 0; ks < 4; ks++) {
      const int kk = ks * 32 + q * 8;
#pragma unroll
      for (int et = 0; et < 8; et++) {
        bf16x8 hb = *(const bf16x8*)(const void*)&sH[swz(et * 16 + col, kk)];
        acc[0][et] = __builtin_amdgcn_mfma_f32_16x16x32_bf16(w2f[0][ks], hb, acc[0][et], 0, 0, 0);
        acc[1][et] = __builtin_amdgcn_mfma_f32_16x16x32_bf16(w2f[1][ks], hb, acc[1][et], 0, 0, 0);
      }
    }
  }
  __syncthreads();  // all layer-2 reads done before h2 overwrites sH

  // ---- layer-2 epilogue: h2 -> sH, packed b64 ----
  {
    float4 blo = *(const float4*)&bm2[wbase + q * 4];
    float4 bhi = *(const float4*)&bm2[wbase + 16 + q * 4];
#pragma unroll
    for (int et = 0; et < 8; et++) {
      const int e = et * 16 + col;
      ushort4v plo, phi;
#pragma unroll
      for (int r = 0; r < 4; r++) {
        plo[r] = tobf(leaky(acc[0][et][r] + ((const float*)&blo)[r]));
        phi[r] = tobf(leaky(acc[1][et][r] + ((const float*)&bhi)[r]));
      }
      *(ushort4v*)(void*)&sH[swz(e, wbase + q * 4)] = plo;
      *(ushort4v*)(void*)&sH[swz(e, wbase + 16 + q * 4)] = phi;
    }
  }
  __syncthreads();  // h2 complete before layer-3 reads

  // ---- layer 3: A = W3 rows, prefetched; B = h2 from LDS ----
  {
    bf16x8 w3f[2][4];
#pragma unroll
    for (int i = 0; i < 2; i++)
#pragma unroll
      for (int ks = 0; ks < 4; ks++)
        w3f[i][ks] = *(const bf16x8*)(const void*)
            &W3bf[(wbase + i * 16 + col) * 128 + ks * 32 + q * 8];
#pragma unroll
    for (int i = 0; i < 2; i++)
#pragma unroll
      for (int j = 0; j < 8; j++) acc[i][j] = (floatx4){0.f, 0.f, 0.f, 0.f};
#pragma unroll
    for (int ks = 0; ks < 4; ks++) {
      const int kk = ks * 32 + q * 8;
#pragma unroll
      for (int et = 0; et < 8; et++) {
        bf16x8 hb = *(const bf16x8*)(const void*)&sH[swz(et * 16 + col, kk)];
        acc[0][et] = __builtin_amdgcn_mfma_f32_16x16x32_bf16(w3f[0][ks], hb, acc[0][et], 0, 0, 0);
        acc[1][et] = __builtin_amdgcn_mfma_f32_16x16x32_bf16(w3f[1][ks], hb, acc[1][et], 0, 0, 0);
      }
    }
  }
  __syncthreads();  // all sH reads done; smem becomes the [128][64] int slab

  // ---- preload this wave's 32 window dsts (lane l -> dst of wave*32 + (l&31)) ----
  const int dmy = sDst[wave * 32 + (lane & 31)];

  // ---- two 64-channel chunks: owning waves write msg (int32, swizzled),
  //      then ALL waves walk their 32-edge window with lane = channel ----
#pragma unroll
  for (int c = 0; c < 2; c++) {
    if ((wave >> 1) == c) {
#pragma unroll
      for (int ci = 0; ci < 2; ci++) {
        float4 b3 = *(const float4*)&bm3[wbase + ci * 16 + q * 4];
        const int cb = (wbase + ci * 16 + q * 4) & 63;
#pragma unroll
        for (int et = 0; et < 8; et++) {
          const int e = et * 16 + col;
          int4 p;
          p.x = __float2int_rn((acc[ci][et][0] + b3.x) * MSG_SCALE);
          p.y = __float2int_rn((acc[ci][et][1] + b3.y) * MSG_SCALE);
          p.z = __float2int_rn((acc[ci][et][2] + b3.z) * MSG_SCALE);
          p.w = __float2int_rn((acc[ci][et][3] + b3.w) * MSG_SCALE);
          *(int4*)(void*)&sMsgI[e * 64 + (cb ^ ((e & 7) << 2))] = p;
        }
      }
    }
    __syncthreads();  // chunk-c msg visible to all waves

    const int e0 = wave * 32;
    const size_t chG = (size_t)c * 64 + lane;
    int accv = 0;
    int dprev = __builtin_amdgcn_readlane(dmy, 0);
#pragma unroll 8
    for (int it = 0; it < 32; it++) {
      const int e = e0 + it;
      const int d = __builtin_amdgcn_readlane(dmy, it);
      const int iv = sMsgI[e * 64 + (lane ^ ((e & 7) << 2))];
      if (d != dprev) {
        atomicAdd(&aggr[(size_t)dprev * 128 + chG], accv);
        accv = 0;
        dprev = d;
      }
      accv += iv;
    }
    atomicAdd(&aggr[(size_t)dprev * 128 + chG], accv);
    if (c == 0) __syncthreads();  // walk-0 done before chunk-1 overwrites slab
  }
}

// ---------------- node layer (swapped-operand MFMA, 64-node blocks; verified) ----
template <int TILES, int CT, int KST, bool FINAL>
__device__ __forceinline__ void layer_node_sw(unsigned short* __restrict__ sX,
                                              const unsigned short* __restrict__ W,
                                              const float* __restrict__ bias, int biasLim,
                                              int wave, int lane, int nodeGBase,
                                              float* __restrict__ out) {
  const int col = lane & 15, q = lane >> 4;
  const int K = KST * 32;
  floatx4 acc[CT][4];
#pragma unroll
  for (int c = 0; c < CT; c++)
#pragma unroll
    for (int n = 0; n < 4; n++) acc[c][n] = (floatx4){0.f, 0.f, 0.f, 0.f};

#pragma unroll
  for (int ks = 0; ks < KST; ks++) {
    const int kk = ks * 32 + q * 8;
    bf16x8 a[CT];
#pragma unroll
    for (int c = 0; c < CT; c++) {
      const int tile = wave + 4 * c;
      const int tc = (tile < TILES) ? tile : 0;  // always defined, always in-bounds
      a[c] = *(const bf16x8*)(const void*)&W[(tc * 16 + col) * K + kk];
    }
    bf16x8 b[4];
#pragma unroll
    for (int n = 0; n < 4; n++)
      b[n] = *(const bf16x8*)(const void*)&sX[(n * 16 + col) * STRN + kk];
#pragma unroll
    for (int c = 0; c < CT; c++) {
      if (wave + 4 * c < TILES) {
#pragma unroll
        for (int n = 0; n < 4; n++)
          acc[c][n] = __builtin_amdgcn_mfma_f32_16x16x32_bf16(a[c], b[n], acc[c][n], 0, 0, 0);
      }
    }
  }
  __syncthreads();  // all waves done reading sX before epilogue overwrites

#pragma unroll
  for (int c = 0; c < CT; c++) {
    const int tile = wave + 4 * c;
    if (tile < TILES) {
      float bv[4];
#pragma unroll
      for (int r = 0; r < 4; r++) {
        const int ch = tile * 16 + q * 4 + r;
        bv[r] = (ch < biasLim) ? bias[ch] : 0.f;
      }
#pragma unroll
      for (int n = 0; n < 4; n++) {
        const int node = n * 16 + col;
        if (!FINAL) {
          ushort4v p;
#pragma unroll
          for (int r = 0; r < 4; r++) p[r] = tobf(leaky(acc[c][n][r] + bv[r]));
          *(ushort4v*)(void*)&sX[node * STRN + tile * 16 + q * 4] = p;
        } else {
          const long ng = (long)nodeGBase + node;
          if (ng < N_NODES) {
            float4 p = make_float4(acc[c][n][0] + bv[0], acc[c][n][1] + bv[1],
                                   acc[c][n][2] + bv[2], acc[c][n][3] + bv[3]);
            *(float4*)(void*)&out[ng * 128 + tile * 16 + q * 4] = p;
          }
        }
      }
    }
  }
  if (!FINAL) __syncthreads();  // writes visible before next layer reads
}

// ---------------- node kernel: LN(concat) + MLP, 64 nodes/block ----------------
// aggr arrives as int32 fixed-point; conversion iv*MSG_INV is deterministic.
__global__ __launch_bounds__(256, 4) void node_kernel(
    const float* __restrict__ x, const int* __restrict__ aggr,
    const float* __restrict__ lng, const float* __restrict__ lnb,
    const unsigned short* __restrict__ Wu1p, const float* __restrict__ bu1,
    const unsigned short* __restrict__ Wu2p, const float* __restrict__ bu2,
    const unsigned short* __restrict__ Wu3p, const float* __restrict__ bu3,
    float* __restrict__ out) {
  __shared__ unsigned short sX[64 * STRN];  // [node][c] bf16, padded stride
  __shared__ float sG[256], sB[256];
  const int t = threadIdx.x;
  const int wave = t >> 6, lane = t & 63;
  sG[t] = lng[t];
  sB[t] = lnb[t];

  // LayerNorm over cat=[x,aggr] (fp32). 4 threads per node.
  const int nl = t >> 2;
  const int part = t & 3;
  const long nodeG = (long)blockIdx.x * 64 + nl;
  const bool valid = nodeG < N_NODES;
  const float* srcF = x + nodeG * 128 + part * 64;
  const int* srcI = aggr + nodeG * 128 + (part - 2) * 64;
  float s = 0.f, ss = 0.f;
  if (valid) {
#pragma unroll
    for (int i = 0; i < 16; i++) {
      float4 a;
      if (part < 2) {
        a = *(const float4*)(srcF + i * 4);
      } else {
        int4 iv = *(const int4*)(srcI + i * 4);
        a = make_float4(iv.x * MSG_INV, iv.y * MSG_INV, iv.z * MSG_INV, iv.w * MSG_INV);
      }
      s += a.x + a.y + a.z + a.w;
      ss += a.x * a.x + a.y * a.y + a.z * a.z + a.w * a.w;
    }
  }
  s += __shfl_xor(s, 1); s += __shfl_xor(s, 2);
  ss += __shfl_xor(ss, 1); ss += __shfl_xor(ss, 2);
  const float mean = s * (1.f / 256.f);
  const float var = ss * (1.f / 256.f) - mean * mean;
  const float rstd = rsqrtf(var + 1e-5f);
  __syncthreads();  // sG/sB visible
  if (valid) {
    const int cb = part * 64;
#pragma unroll
    for (int i = 0; i < 16; i++) {
      float4 a;
      if (part < 2) {
        a = *(const float4*)(srcF + i * 4);
      } else {
        int4 iv = *(const int4*)(srcI + i * 4);
        a = make_float4(iv.x * MSG_INV, iv.y * MSG_INV, iv.z * MSG_INV, iv.w * MSG_INV);
      }
      int c = cb + i * 4;
      ushort4v p;
      p[0] = tobf((a.x - mean) * rstd * sG[c + 0] + sB[c + 0]);
      p[1] = tobf((a.y - mean) * rstd * sG[c + 1] + sB[c + 1]);
      p[2] = tobf((a.z - mean) * rstd * sG[c + 2] + sB[c + 2]);
      p[3] = tobf((a.w - mean) * rstd * sG[c + 3] + sB[c + 3]);
      *(ushort4v*)(void*)&sX[nl * STRN + c] = p;
    }
  }
  __syncthreads();

  const int nodeGBase = blockIdx.x * 64;
  layer_node_sw<14, 4, 8, false>(sX, Wu1p, bu1, 214, wave, lane, nodeGBase, nullptr);
  layer_node_sw<12, 3, 7, false>(sX, Wu2p, bu2, 172, wave, lane, nodeGBase, nullptr);
  layer_node_sw<8, 2, 6, true>(sX, Wu3p, bu3, 128, wave, lane, nodeGBase, out);
}

// ---------------- launch ----------------
extern "C" void kernel_launch(void* const* d_in, const int* in_sizes, int n_in,
                              void* d_out, int out_size, void* d_ws, size_t ws_size,
                              hipStream_t stream) {
  const float* x    = (const float*)d_in[0];
  const int*   eidx = (const int*)d_in[1];
  const float* attr = (const float*)d_in[2];
  const float* Wm1  = (const float*)d_in[3];
  const float* bm1  = (const float*)d_in[4];
  const float* Wm2  = (const float*)d_in[5];
  const float* bm2  = (const float*)d_in[6];
  const float* Wm3  = (const float*)d_in[7];
  const float* bm3  = (const float*)d_in[8];
  const float* lng  = (const float*)d_in[9];
  const float* lnb  = (const float*)d_in[10];
  const float* Wu1  = (const float*)d_in[11];
  const float* bu1  = (const float*)d_in[12];
  const float* Wu2  = (const float*)d_in[13];
  const float* bu2  = (const float*)d_in[14];
  const float* Wu3  = (const float*)d_in[15];
  const float* bu3  = (const float*)d_in[16];
  float* out = (float*)d_out;

  char* ws = (char*)d_ws;
  int* aggr    = (int*)(ws + WS_AGGR);
  int* counts  = (int*)(ws + WS_COUNTS);
  int* offs    = (int*)(ws + WS_OFFS);
  int* parts   = (int*)(ws + WS_PART);
  int* rank    = (int*)(ws + WS_RANK);
  unsigned short* attrB = (unsigned short*)(ws + WS_ATTRS);
  unsigned short* W2bf = (unsigned short*)(ws + WS_W2);
  unsigned short* W3bf = (unsigned short*)(ws + WS_W3);
  unsigned short* Wu1p = (unsigned short*)(ws + WS_WU1);
  unsigned short* Wu2p = (unsigned short*)(ws + WS_WU2);
  unsigned short* Wu3p = (unsigned short*)(ws + WS_WU3);
  unsigned short* W1bf = (unsigned short*)(ws + WS_W1);

  const int* dst = eidx + N_EDGES;  // edge_index[1]

  // counting sort of edges by dst. hist (fused with weight prep) records
  // ranks; scatter is atomic-free (scanC fused via parts[d>>8]), writes one
  // 16B record per edge with d embedded, and zeroes aggr inline.
  hipMemsetAsync(counts, 0, 400384, stream);
  hist_prep_kernel<<<6250, 256, 0, stream>>>(dst, counts, rank,
                                             Wm1, Wm2, Wm3, Wu1, Wu2, Wu3,
                                             W1bf, W2bf, W3bf, Wu1p, Wu2p, Wu3p);
  scanA_kernel<<<NBLK_SCAN, 256, 0, stream>>>(counts, offs, parts);
  scanB_kernel<<<1, 512, 0, stream>>>(parts);
  scatter_kernel<<<6250, 256, 0, stream>>>(dst, offs, parts, rank, attr, attrB, aggr);

  edge_kernel<<<N_EDGES / 128, 256, 0, stream>>>(attrB, W1bf, bm1, W2bf, bm2, W3bf,
                                                 bm3, aggr);
  node_kernel<<<(N_NODES + 63) / 64, 256, 0, stream>>>(x, aggr, lng, lnb, Wu1p, bu1, Wu2p, bu2,
                                                       Wu3p, bu3, out);
}